// Round 1
// baseline (2488.536 us; speedup 1.0000x reference)
//
#include <hip/hip_runtime.h>
#include <cstdint>
#include <cstddef>

// ---------------------------------------------------------------------------
// GATv2 x3 + master pooling.  f32 correctness-first implementation.
// Pipeline per layer:
//   gemm_f32 (xl = A@wl), gemm_f32 (xr = A@wr)
//   edge_logits_k: per-edge  logits[e,h] = sum_c lrelu(xl[src]+xr[dst]+ea@we)*att
//   aggregate_k:   per-node segment softmax over incoming edges + weighted sum
// CSR over dst built once per call (histogram + scan + scatter).
// ---------------------------------------------------------------------------

// ---------------- CSR build ----------------
__global__ __launch_bounds__(256) void hist_k(const int* __restrict__ dst,
                                              int* __restrict__ counts, int E) {
  int e = blockIdx.x * 256 + threadIdx.x;
  if (e < E) atomicAdd(&counts[dst[e]], 1);
}

__global__ __launch_bounds__(1024) void scan_k(const int* __restrict__ counts,
                                               int* __restrict__ rowptr,
                                               int* __restrict__ cursor, int N) {
  __shared__ int sums[1024];
  const int t = threadIdx.x;
  const int per = (N + 1023) >> 10;
  const int i0 = t * per;
  const int i1 = min(i0 + per, N);
  int s = 0;
  for (int i = i0; i < i1; ++i) s += counts[i];
  sums[t] = s;
  __syncthreads();
  // Hillis-Steele inclusive scan over 1024 partial sums
  for (int off = 1; off < 1024; off <<= 1) {
    int v = (t >= off) ? sums[t - off] : 0;
    __syncthreads();
    sums[t] += v;
    __syncthreads();
  }
  int run = t ? sums[t - 1] : 0;
  for (int i = i0; i < i1; ++i) {
    rowptr[i] = run;
    cursor[i] = run;
    run += counts[i];
  }
  if (t == 1023) rowptr[N] = sums[1023];
}

__global__ __launch_bounds__(256) void scatter_k(const int* __restrict__ dst,
                                                 int* __restrict__ cursor,
                                                 int* __restrict__ csr, int E) {
  int e = blockIdx.x * 256 + threadIdx.x;
  if (e < E) {
    int p = atomicAdd(&cursor[dst[e]], 1);
    csr[p] = e;
  }
}

// master node = last index of each (sorted) batch segment
__global__ __launch_bounds__(256) void master_k(const int* __restrict__ batch,
                                                int* __restrict__ master, int N) {
  int i = blockIdx.x * 256 + threadIdx.x;
  if (i < N) {
    int b = batch[i];
    if (i == N - 1 || batch[i + 1] != b) master[b] = i;
  }
}

// ---------------- GEMM: C[M,256] = A[M,K] @ W[K,256] ----------------
// BM=BN=64, BK=16, 256 threads, 4x4 per thread.
__global__ __launch_bounds__(256) void gemm_f32(const float* __restrict__ A,
                                                const float* __restrict__ W,
                                                float* __restrict__ C,
                                                int M, int K) {
  const int bm = blockIdx.x * 64;
  const int bn = blockIdx.y * 64;
  const int tid = threadIdx.x;

  __shared__ float As[16][68];  // [k][m], padded
  __shared__ float Bs[16][68];  // [k][n], padded

  const int tm = (tid >> 4) * 4;  // 0..60
  const int tn = (tid & 15) * 4;  // 0..60

  const int arow = tid >> 2;        // 0..63
  const int ak4  = (tid & 3) * 4;   // 0,4,8,12
  const int wrow = tid >> 4;        // 0..15
  const int wc4  = (tid & 15) * 4;  // 0..60
  const int gr = bm + arow;

  float acc[4][4] = {};

  for (int k0 = 0; k0 < K; k0 += 16) {
    float4 av = make_float4(0.f, 0.f, 0.f, 0.f);
    if (gr < M) av = *(const float4*)(A + (size_t)gr * K + k0 + ak4);
    float4 wv = *(const float4*)(W + (size_t)(k0 + wrow) * 256 + bn + wc4);
    __syncthreads();  // protect previous iteration's LDS reads
    As[ak4 + 0][arow] = av.x;
    As[ak4 + 1][arow] = av.y;
    As[ak4 + 2][arow] = av.z;
    As[ak4 + 3][arow] = av.w;
    *(float4*)&Bs[wrow][wc4] = wv;
    __syncthreads();
#pragma unroll
    for (int k = 0; k < 16; ++k) {
      float4 a4 = *(const float4*)&As[k][tm];
      float4 b4 = *(const float4*)&Bs[k][tn];
      acc[0][0] += a4.x * b4.x; acc[0][1] += a4.x * b4.y; acc[0][2] += a4.x * b4.z; acc[0][3] += a4.x * b4.w;
      acc[1][0] += a4.y * b4.x; acc[1][1] += a4.y * b4.y; acc[1][2] += a4.y * b4.z; acc[1][3] += a4.y * b4.w;
      acc[2][0] += a4.z * b4.x; acc[2][1] += a4.z * b4.y; acc[2][2] += a4.z * b4.z; acc[2][3] += a4.z * b4.w;
      acc[3][0] += a4.w * b4.x; acc[3][1] += a4.w * b4.y; acc[3][2] += a4.w * b4.z; acc[3][3] += a4.w * b4.w;
    }
  }
#pragma unroll
  for (int i = 0; i < 4; ++i) {
    int r = bm + tm + i;
    if (r < M) {
      float4 v = make_float4(acc[i][0], acc[i][1], acc[i][2], acc[i][3]);
      *(float4*)(C + (size_t)r * 256 + bn + tn) = v;
    }
  }
}

// ---------------- edge logits ----------------
// grid.x = chunks of 64 edges, grid.y = head (2). 256 threads.
// thread t: sub = t>>7 (which of 2 concurrent edges), c = t&127 (column).
// we column (64 f32) cached in registers; edge_attr chunk staged in LDS.
#define EPCH 64
__global__ __launch_bounds__(256) void edge_logits_k(
    const float* __restrict__ xl, const float* __restrict__ xr,
    const float* __restrict__ eattr, const float* __restrict__ we,
    const float* __restrict__ att, const int* __restrict__ src,
    const int* __restrict__ dst, float* __restrict__ logits, int E) {
  __shared__ float4 ea4s[EPCH * 16];       // 64 edges x 64 f32 = 16KB
  __shared__ float red[EPCH / 2][4];       // per-iteration per-wave partials

  const int tid = threadIdx.x;
  const int h = blockIdx.y;
  const int sub = tid >> 7;   // 0/1
  const int c = tid & 127;
  const int wv = tid >> 6;    // wave 0..3

  // we[:, h*128 + c] into registers (reused for all 64 edges of the chunk)
  float w[64];
#pragma unroll
  for (int d = 0; d < 64; ++d) w[d] = we[(size_t)d * 256 + (h << 7) + c];
  const float attv = att[(h << 7) + c];

  const int e0 = blockIdx.x * EPCH;

  // stage edge_attr rows for this chunk (coalesced float4)
  {
    const float4* g = (const float4*)(eattr + (size_t)e0 * 64);
    const int lim4 = (E - e0) * 16;  // valid float4 count
#pragma unroll
    for (int k = tid; k < EPCH * 16; k += 256)
      ea4s[k] = (k < lim4) ? g[k] : make_float4(0.f, 0.f, 0.f, 0.f);
  }
  __syncthreads();

#pragma unroll 1
  for (int i = 0; i < EPCH / 2; ++i) {
    const int el = i * 2 + sub;
    const int e = e0 + el;
    const float4* erow = ea4s + el * 16;
    float acc = 0.f;
#pragma unroll
    for (int q = 0; q < 16; ++q) {
      float4 v = erow[q];  // broadcast (uniform address within 128-group)
      acc += v.x * w[4 * q + 0];
      acc += v.y * w[4 * q + 1];
      acc += v.z * w[4 * q + 2];
      acc += v.w * w[4 * q + 3];
    }
    float gsum = 0.f;
    if (e < E) {
      const int s_ = src[e], d_ = dst[e];
      acc += xl[(size_t)s_ * 256 + (h << 7) + c] + xr[(size_t)d_ * 256 + (h << 7) + c];
      acc = (acc > 0.f) ? acc : 0.2f * acc;  // leaky_relu 0.2
      gsum = acc * attv;
    }
#pragma unroll
    for (int off = 32; off; off >>= 1) gsum += __shfl_down(gsum, off);
    if ((tid & 63) == 0) red[i][wv] = gsum;
  }
  __syncthreads();
  // finalize: thread t < 64 writes edge el = t
  if (tid < EPCH) {
    const int e = e0 + tid;
    if (e < E) {
      const int i = tid >> 1, s2 = tid & 1;
      logits[(size_t)e * 2 + h] = red[i][s2 * 2] + red[i][s2 * 2 + 1];
    }
  }
}

// ---------------- per-node segment softmax + aggregation ----------------
// one wave (64 lanes) per node; lane covers output cols c=lane and c=64+lane,
// accumulating both heads.
__global__ __launch_bounds__(256) void aggregate_k(
    const float* __restrict__ xl, const float* __restrict__ logits,
    const int* __restrict__ rowptr, const int* __restrict__ csr,
    const int* __restrict__ src, const float* __restrict__ bias,
    float* __restrict__ hout, int N, int do_relu) {
  const int n = blockIdx.x * 4 + (threadIdx.x >> 6);
  if (n >= N) return;
  const int lane = threadIdx.x & 63;
  const int beg = rowptr[n], end = rowptr[n + 1];

  float m0 = -1e30f, m1 = -1e30f;
  for (int i = beg; i < end; ++i) {
    const int e = csr[i];
    m0 = fmaxf(m0, logits[(size_t)e * 2 + 0]);
    m1 = fmaxf(m1, logits[(size_t)e * 2 + 1]);
  }
  float s0 = 0.f, s1 = 0.f;
  float a00 = 0.f, a01 = 0.f, a10 = 0.f, a11 = 0.f;
  for (int i = beg; i < end; ++i) {
    const int e = csr[i];
    const float w0 = __expf(logits[(size_t)e * 2 + 0] - m0);
    const float w1 = __expf(logits[(size_t)e * 2 + 1] - m1);
    s0 += w0; s1 += w1;
    const float* xs = xl + (size_t)src[e] * 256;
    a00 += w0 * xs[lane];        // head0, col lane
    a01 += w0 * xs[64 + lane];   // head0, col 64+lane
    a10 += w1 * xs[128 + lane];  // head1, col lane
    a11 += w1 * xs[192 + lane];  // head1, col 64+lane
  }
  const float inv0 = 1.f / (s0 + 1e-16f);
  const float inv1 = 1.f / (s1 + 1e-16f);
  float o0 = 0.5f * (a00 * inv0 + a10 * inv1) + bias[lane];
  float o1 = 0.5f * (a01 * inv0 + a11 * inv1) + bias[64 + lane];
  if (do_relu) { o0 = fmaxf(o0, 0.f); o1 = fmaxf(o1, 0.f); }
  hout[(size_t)n * 128 + lane] = o0;
  hout[(size_t)n * 128 + 64 + lane] = o1;
}

// ---------------- final pooling gather ----------------
__global__ __launch_bounds__(128) void gather_k(const float* __restrict__ h,
                                                const int* __restrict__ master,
                                                float* __restrict__ out) {
  const int b = blockIdx.x;
  const int c = threadIdx.x;
  out[(size_t)b * 128 + c] = h[(size_t)master[b] * 128 + c];
}

// ---------------------------------------------------------------------------
extern "C" void kernel_launch(void* const* d_in, const int* in_sizes, int n_in,
                              void* d_out, int out_size, void* d_ws, size_t ws_size,
                              hipStream_t stream) {
  const float* x     = (const float*)d_in[0];
  const int*   ei    = (const int*)d_in[1];
  const float* eattr = (const float*)d_in[2];
  const int*   batch = (const int*)d_in[3];

  const int N  = in_sizes[3];
  const int E  = in_sizes[1] / 2;
  const int IN = in_sizes[0] / N;
  const int B  = out_size / 128;

  const int* src = ei;
  const int* dstp = ei + E;

  // workspace carve (256B aligned)
  char* p = (char*)d_ws;
  auto carve = [&](size_t bytes) {
    void* r = (void*)p;
    p += (bytes + 255) & ~(size_t)255;
    return r;
  };
  float* xl     = (float*)carve((size_t)N * 256 * sizeof(float));
  float* xr     = (float*)carve((size_t)N * 256 * sizeof(float));
  float* h1     = (float*)carve((size_t)N * 128 * sizeof(float));
  float* h2     = (float*)carve((size_t)N * 128 * sizeof(float));
  float* logits = (float*)carve((size_t)E * 2 * sizeof(float));
  int* counts   = (int*)carve(((size_t)N + B) * sizeof(int));
  int* master   = counts + N;
  int* rowptr   = (int*)carve(((size_t)N + 1) * sizeof(int));
  int* cursor   = (int*)carve((size_t)N * sizeof(int));
  int* csr      = (int*)carve((size_t)E * sizeof(int));
  (void)ws_size; (void)n_in;

  // CSR over dst + master nodes (once; reused by all 3 layers)
  hipMemsetAsync(counts, 0, ((size_t)N + B) * sizeof(int), stream);
  hist_k<<<(E + 255) / 256, 256, 0, stream>>>(dstp, counts, E);
  scan_k<<<1, 1024, 0, stream>>>(counts, rowptr, cursor, N);
  scatter_k<<<(E + 255) / 256, 256, 0, stream>>>(dstp, cursor, csr, E);
  master_k<<<(N + 255) / 256, 256, 0, stream>>>(batch, master, N);

  dim3 gemm_grid((N + 63) / 64, 4);
  dim3 edge_grid((E + EPCH - 1) / EPCH, 2);
  const int agg_grid = (N + 3) / 4;

  const float* Ain = x;
  int K = IN;
  float* houts[3] = {h1, h2, h1};  // layer3 reuses h1 (free after layer2 GEMMs)
  for (int l = 0; l < 3; ++l) {
    const float* wl  = (const float*)d_in[4 + 5 * l + 0];
    const float* wr  = (const float*)d_in[4 + 5 * l + 1];
    const float* we  = (const float*)d_in[4 + 5 * l + 2];
    const float* att = (const float*)d_in[4 + 5 * l + 3];
    const float* bv  = (const float*)d_in[4 + 5 * l + 4];

    gemm_f32<<<gemm_grid, 256, 0, stream>>>(Ain, wl, xl, N, K);
    gemm_f32<<<gemm_grid, 256, 0, stream>>>(Ain, wr, xr, N, K);
    edge_logits_k<<<edge_grid, 256, 0, stream>>>(xl, xr, eattr, we, att, src, dstp, logits, E);
    aggregate_k<<<agg_grid, 256, 0, stream>>>(xl, logits, rowptr, csr, src, bv,
                                              houts[l], N, l < 2 ? 1 : 0);
    Ain = houts[l];
    K = 128;
  }

  gather_k<<<B, 128, 0, stream>>>(h1, master, (float*)d_out);
}

// Round 2
// 1475.438 us; speedup vs baseline: 1.6866x; 1.6866x over previous
//
#include <hip/hip_runtime.h>
#include <cstdint>
#include <cstddef>

// ---------------------------------------------------------------------------
// GATv2 x3 + master pooling, bf16-MFMA edition.
// Per layer:
//   xlr = bf16(A) @ bf16([wl|wr])            (MFMA GEMM, N=512)
//   eproj = bf16(edge_attr) @ bf16(we)       (MFMA GEMM, chunked over E)
//   logits_k: elementwise lrelu(xl[s]+xr[d]+eproj)·att, wave/edge reduce
//   aggregate_k: CSR segment softmax + weighted gather-sum (f32 accum)
// ---------------------------------------------------------------------------

typedef __attribute__((ext_vector_type(8))) short bf16x8;
typedef __attribute__((ext_vector_type(4))) float f32x4;

static __device__ __forceinline__ ushort f2b(float f) {
  uint32_t u = __float_as_uint(f);
  uint32_t r = (u + 0x7fffu + ((u >> 16) & 1u)) >> 16;  // RNE
  return (ushort)r;
}
static __device__ __forceinline__ float b2f(ushort b) {
  return __uint_as_float(((uint32_t)b) << 16);
}

// ---------------- CSR build ----------------
__global__ __launch_bounds__(256) void hist_k(const int* __restrict__ dst,
                                              int* __restrict__ counts, int E) {
  int e = blockIdx.x * 256 + threadIdx.x;
  if (e < E) atomicAdd(&counts[dst[e]], 1);
}

__global__ __launch_bounds__(1024) void scan_k(const int* __restrict__ counts,
                                               int* __restrict__ rowptr,
                                               int* __restrict__ cursor, int N) {
  __shared__ int sums[1024];
  const int t = threadIdx.x;
  const int per = (N + 1023) >> 10;
  const int i0 = t * per;
  const int i1 = min(i0 + per, N);
  int s = 0;
  for (int i = i0; i < i1; ++i) s += counts[i];
  sums[t] = s;
  __syncthreads();
  for (int off = 1; off < 1024; off <<= 1) {
    int v = (t >= off) ? sums[t - off] : 0;
    __syncthreads();
    sums[t] += v;
    __syncthreads();
  }
  int run = t ? sums[t - 1] : 0;
  for (int i = i0; i < i1; ++i) {
    rowptr[i] = run;
    cursor[i] = run;
    run += counts[i];
  }
  if (t == 1023) rowptr[N] = sums[1023];
}

__global__ __launch_bounds__(256) void scatter_k(const int* __restrict__ dst,
                                                 int* __restrict__ cursor,
                                                 int* __restrict__ csr, int E) {
  int e = blockIdx.x * 256 + threadIdx.x;
  if (e < E) {
    int p = atomicAdd(&cursor[dst[e]], 1);
    csr[p] = e;
  }
}

__global__ __launch_bounds__(256) void master_k(const int* __restrict__ batch,
                                                int* __restrict__ master, int N) {
  int i = blockIdx.x * 256 + threadIdx.x;
  if (i < N) {
    int b = batch[i];
    if (i == N - 1 || batch[i + 1] != b) master[b] = i;
  }
}

// ---------------- conversions ----------------
__global__ __launch_bounds__(256) void cvt_k(const float* __restrict__ in,
                                             ushort* __restrict__ out, int n4) {
  int i = blockIdx.x * 256 + threadIdx.x;
  if (i < n4) {
    float4 v = ((const float4*)in)[i];
    ushort4 o;
    o.x = f2b(v.x); o.y = f2b(v.y); o.z = f2b(v.z); o.w = f2b(v.w);
    ((ushort4*)out)[i] = o;
  }
}

// out[(row_off+n)*K + k] = bf16(W[k*N + n])   (transpose+convert; tiny)
__global__ __launch_bounds__(256) void wt_k(const float* __restrict__ W,
                                            ushort* __restrict__ out,
                                            int K, int N, int row_off) {
  int i = blockIdx.x * 256 + threadIdx.x;
  if (i < N * K) {
    int n = i / K, k = i - n * K;
    out[(size_t)(row_off + n) * K + k] = f2b(W[(size_t)k * N + n]);
  }
}

// ---------------- bf16 MFMA GEMM ----------------
// C[M,N] = A[M,K] @ Bt[N,K]^T. 128x128 tile, BK=64, 4 waves (2x2), 64x64/wave.
// XOR-swizzled LDS (kslot ^= row&7) -> conflict-free ds_write_b128/ds_read_b128.
__global__ __launch_bounds__(256) void gemm_bf16(const ushort* __restrict__ A,
                                                 const ushort* __restrict__ Bt,
                                                 ushort* __restrict__ C,
                                                 int M, int N, int K) {
  __shared__ ushort As[128 * 64];
  __shared__ ushort Bs[128 * 64];
  const int tid = threadIdx.x;
  const int lane = tid & 63;
  const int wave = tid >> 6;
  const int bm = blockIdx.x * 128;
  const int bn = blockIdx.y * 128;
  const int wm = (wave >> 1) * 64;
  const int wn = (wave & 1) * 64;
  const int l15 = lane & 15;
  const int t_hi = lane >> 4;

  f32x4 acc[4][4] = {};

  const int st_r0 = tid >> 3;  // 0..31 (row within 32-row issue group)
  const int st_c8 = tid & 7;   // 16B k-slot
  const int st_cs = st_c8 ^ (st_r0 & 7);  // swizzled LDS k-slot

  for (int k0 = 0; k0 < K; k0 += 64) {
    uint4 ra[4], rb[4];
#pragma unroll
    for (int i = 0; i < 4; ++i) {
      int r = i * 32 + st_r0;
      int ar = bm + r; ar = ar < M ? ar : M - 1;  // clamp tail (masked on store)
      ra[i] = *(const uint4*)(A + (size_t)ar * K + k0 + st_c8 * 8);
      rb[i] = *(const uint4*)(Bt + (size_t)(bn + r) * K + k0 + st_c8 * 8);
    }
    __syncthreads();
#pragma unroll
    for (int i = 0; i < 4; ++i) {
      int r = i * 32 + st_r0;
      *(uint4*)&As[r * 64 + st_cs * 8] = ra[i];
      *(uint4*)&Bs[r * 64 + st_cs * 8] = rb[i];
    }
    __syncthreads();
#pragma unroll
    for (int ks = 0; ks < 2; ++ks) {
      bf16x8 af[4], bfr[4];
#pragma unroll
      for (int f = 0; f < 4; ++f) {
        const int q = (ks * 4 + t_hi) ^ (lane & 7);
        af[f]  = *(const bf16x8*)&As[(wm + f * 16 + l15) * 64 + q * 8];
        bfr[f] = *(const bf16x8*)&Bs[(wn + f * 16 + l15) * 64 + q * 8];
      }
#pragma unroll
      for (int fm = 0; fm < 4; ++fm)
#pragma unroll
        for (int fn = 0; fn < 4; ++fn)
          acc[fm][fn] = __builtin_amdgcn_mfma_f32_16x16x32_bf16(
              af[fm], bfr[fn], acc[fm][fn], 0, 0, 0);
    }
  }
#pragma unroll
  for (int fm = 0; fm < 4; ++fm) {
    const int r0 = bm + wm + fm * 16 + t_hi * 4;
#pragma unroll
    for (int j = 0; j < 4; ++j) {
      const int gr = r0 + j;
      if (gr < M) {
#pragma unroll
        for (int fn = 0; fn < 4; ++fn) {
          const int gc = bn + wn + fn * 16 + l15;
          C[(size_t)gr * N + gc] = f2b(acc[fm][fn][j]);
        }
      }
    }
  }
}

// ---------------- edge logits (elementwise) ----------------
// one wave per edge: q = lrelu(eproj[e] + xl[src] + xr[dst]); logit[h]=sum q*att
__global__ __launch_bounds__(256) void logits_k(
    const ushort* __restrict__ xlr, const ushort* __restrict__ eproj,
    const float* __restrict__ att, const int* __restrict__ src,
    const int* __restrict__ dst, float* __restrict__ logits,
    int e0, int e1) {
  const int lane = threadIdx.x & 63;
  const int gw = (int)((blockIdx.x * blockDim.x + threadIdx.x) >> 6);
  const int nw = (int)((gridDim.x * blockDim.x) >> 6);
  const float a0 = att[4 * lane + 0], a1 = att[4 * lane + 1];
  const float a2 = att[4 * lane + 2], a3 = att[4 * lane + 3];
  for (int e = e0 + gw; e < e1; e += nw) {
    const int s = src[e], d = dst[e];
    ushort4 ue = *(const ushort4*)(eproj + (((size_t)(e - e0)) << 8) + lane * 4);
    ushort4 us = *(const ushort4*)(xlr + (((size_t)s) << 9) + lane * 4);
    ushort4 ud = *(const ushort4*)(xlr + (((size_t)d) << 9) + 256 + lane * 4);
    float q0 = b2f(ue.x) + b2f(us.x) + b2f(ud.x);
    float q1 = b2f(ue.y) + b2f(us.y) + b2f(ud.y);
    float q2 = b2f(ue.z) + b2f(us.z) + b2f(ud.z);
    float q3 = b2f(ue.w) + b2f(us.w) + b2f(ud.w);
    q0 = q0 > 0.f ? q0 : 0.2f * q0;
    q1 = q1 > 0.f ? q1 : 0.2f * q1;
    q2 = q2 > 0.f ? q2 : 0.2f * q2;
    q3 = q3 > 0.f ? q3 : 0.2f * q3;
    float p = q0 * a0 + q1 * a1 + q2 * a2 + q3 * a3;
    p += __shfl_xor(p, 1);
    p += __shfl_xor(p, 2);
    p += __shfl_xor(p, 4);
    p += __shfl_xor(p, 8);
    p += __shfl_xor(p, 16);
    if ((lane & 31) == 0) logits[2 * (size_t)e + (lane >> 5)] = p;
  }
}

// ---------------- per-node segment softmax + aggregation ----------------
__global__ __launch_bounds__(256) void aggregate_k(
    const ushort* __restrict__ xlr, const float* __restrict__ logits,
    const int* __restrict__ rowptr, const int* __restrict__ csr,
    const int* __restrict__ src, const float* __restrict__ bias,
    ushort* __restrict__ hb, float* __restrict__ hf, int N, int relu) {
  const int n = blockIdx.x * 4 + (threadIdx.x >> 6);
  if (n >= N) return;
  const int lane = threadIdx.x & 63;
  const int beg = rowptr[n], end = rowptr[n + 1];
  float m0 = -1e30f, m1 = -1e30f;
  for (int i = beg; i < end; ++i) {
    const int e = csr[i];
    m0 = fmaxf(m0, logits[2 * (size_t)e]);
    m1 = fmaxf(m1, logits[2 * (size_t)e + 1]);
  }
  float s0 = 0.f, s1 = 0.f, a00 = 0.f, a01 = 0.f, a10 = 0.f, a11 = 0.f;
  for (int i = beg; i < end; ++i) {
    const int e = csr[i];
    const float w0 = __expf(logits[2 * (size_t)e] - m0);
    const float w1 = __expf(logits[2 * (size_t)e + 1] - m1);
    s0 += w0; s1 += w1;
    const ushort* xs = xlr + (((size_t)src[e]) << 9);
    a00 += w0 * b2f(xs[lane]);
    a01 += w0 * b2f(xs[64 + lane]);
    a10 += w1 * b2f(xs[128 + lane]);
    a11 += w1 * b2f(xs[192 + lane]);
  }
  const float i0 = 1.f / (s0 + 1e-16f), i1 = 1.f / (s1 + 1e-16f);
  float o0 = 0.5f * (a00 * i0 + a10 * i1) + bias[lane];
  float o1 = 0.5f * (a01 * i0 + a11 * i1) + bias[64 + lane];
  if (relu) { o0 = fmaxf(o0, 0.f); o1 = fmaxf(o1, 0.f); }
  hb[(size_t)n * 128 + lane] = f2b(o0);
  hb[(size_t)n * 128 + 64 + lane] = f2b(o1);
  if (hf) {
    hf[(size_t)n * 128 + lane] = o0;
    hf[(size_t)n * 128 + 64 + lane] = o1;
  }
}

__global__ __launch_bounds__(128) void gather_k(const float* __restrict__ h,
                                                const int* __restrict__ master,
                                                float* __restrict__ out) {
  out[(size_t)blockIdx.x * 128 + threadIdx.x] =
      h[(size_t)master[blockIdx.x] * 128 + threadIdx.x];
}

// ---------------------------------------------------------------------------
#define CHUNK_E 100352  // 784 * 128

extern "C" void kernel_launch(void* const* d_in, const int* in_sizes, int n_in,
                              void* d_out, int out_size, void* d_ws, size_t ws_size,
                              hipStream_t stream) {
  const float* x     = (const float*)d_in[0];
  const int*   ei    = (const int*)d_in[1];
  const float* eattr = (const float*)d_in[2];
  const int*   batch = (const int*)d_in[3];

  const int N  = in_sizes[3];
  const int E  = in_sizes[1] / 2;
  const int IN = in_sizes[0] / N;
  const int B  = out_size / 128;

  const int* src  = ei;
  const int* dstp = ei + E;

  char* p = (char*)d_ws;
  auto carve = [&](size_t bytes) {
    void* r = (void*)p;
    p += (bytes + 255) & ~(size_t)255;
    return r;
  };
  ushort* xb    = (ushort*)carve((size_t)N * 512 * 2);   // bf16(x); dead after L1 GEMM
  ushort* eb    = (ushort*)carve((size_t)E * 64 * 2);    // bf16(edge_attr)
  ushort* xlr   = (ushort*)carve((size_t)N * 512 * 2);   // [xl | xr] bf16
  ushort* eproj = (ushort*)carve((size_t)CHUNK_E * 256 * 2);
  ushort* h1b   = (ushort*)carve((size_t)N * 128 * 2);
  ushort* h2b   = (ushort*)carve((size_t)N * 128 * 2);
  ushort* wt    = (ushort*)carve((size_t)512 * 512 * 2); // [wl|wr]^T bf16
  ushort* wet   = (ushort*)carve((size_t)256 * 64 * 2);  // we^T bf16
  float* logits = (float*)carve((size_t)E * 2 * 4);
  int* counts   = (int*)carve(((size_t)N + B) * 4);
  int* master   = counts + N;
  int* rowptr   = (int*)carve(((size_t)N + 1) * 4);
  int* cursor   = (int*)carve((size_t)N * 4);
  int* csr      = (int*)carve((size_t)E * 4);
  float* hf     = (float*)xb;  // f32 h3 aliases dead xb
  (void)ws_size; (void)n_in;

  // CSR + masters (reused by all 3 layers)
  hipMemsetAsync(counts, 0, ((size_t)N + B) * 4, stream);
  hist_k<<<(E + 255) / 256, 256, 0, stream>>>(dstp, counts, E);
  scan_k<<<1, 1024, 0, stream>>>(counts, rowptr, cursor, N);
  scatter_k<<<(E + 255) / 256, 256, 0, stream>>>(dstp, cursor, csr, E);
  master_k<<<(N + 255) / 256, 256, 0, stream>>>(batch, master, N);

  // bf16 conversions of the big inputs
  {
    int n4 = N * IN / 4;
    cvt_k<<<(n4 + 255) / 256, 256, 0, stream>>>(x, xb, n4);
    int e4 = E * 64 / 4;
    cvt_k<<<(e4 + 255) / 256, 256, 0, stream>>>(eattr, eb, e4);
  }

  const int agg_grid = (N + 3) / 4;
  for (int l = 0; l < 3; ++l) {
    const float* wl  = (const float*)d_in[4 + 5 * l + 0];
    const float* wr  = (const float*)d_in[4 + 5 * l + 1];
    const float* we  = (const float*)d_in[4 + 5 * l + 2];
    const float* att = (const float*)d_in[4 + 5 * l + 3];
    const float* bv  = (const float*)d_in[4 + 5 * l + 4];
    const int K = (l == 0) ? IN : 128;

    // weights -> bf16 transposed [n][k]
    wt_k<<<(256 * K + 255) / 256, 256, 0, stream>>>(wl, wt, K, 256, 0);
    wt_k<<<(256 * K + 255) / 256, 256, 0, stream>>>(wr, wt, K, 256, 256);
    wt_k<<<(256 * 64 + 255) / 256, 256, 0, stream>>>(we, wet, 64, 256, 0);

    const ushort* Ab = (l == 0) ? xb : ((l == 1) ? h1b : h2b);
    gemm_bf16<<<dim3((N + 127) / 128, 4), 256, 0, stream>>>(Ab, wt, xlr, N, 512, K);

    // edge projection + logits, chunked
    for (int c0 = 0; c0 < E; c0 += CHUNK_E) {
      const int Mc = min(CHUNK_E, E - c0);
      gemm_bf16<<<dim3((Mc + 127) / 128, 2), 256, 0, stream>>>(
          eb + (size_t)c0 * 64, wet, eproj, Mc, 256, 64);
      logits_k<<<1024, 256, 0, stream>>>(xlr, eproj, att, src, dstp, logits,
                                         c0, c0 + Mc);
    }

    ushort* hb = (l == 0) ? h1b : ((l == 1) ? h2b : h1b);
    aggregate_k<<<agg_grid, 256, 0, stream>>>(xlr, logits, rowptr, csr, src, bv,
                                              hb, (l == 2) ? hf : nullptr, N,
                                              l < 2 ? 1 : 0);
  }

  gather_k<<<B, 128, 0, stream>>>(hf, master, (float*)d_out);
}

// Round 3
// 1171.719 us; speedup vs baseline: 2.1238x; 1.2592x over previous
//
#include <hip/hip_runtime.h>
#include <cstdint>
#include <cstddef>

// ---------------------------------------------------------------------------
// GATv2 x3 + master pooling, bf16-MFMA edition.
// Per layer:
//   xlr = bf16(A) @ bf16([wl|wr])            (MFMA GEMM, N=512)
//   eproj = bf16(edge_attr) @ bf16(we)       (MFMA GEMM, chunked over E)
//   logits_k: elementwise lrelu(xl[s]+xr[d]+eproj)·att, wave/edge reduce
//   aggregate_k: CSR segment softmax + weighted gather-sum (f32 accum)
// GEMM staging uses global_load_lds (no staging VGPRs -> no scratch spill);
// bank-conflict swizzle is applied on the global SOURCE address (rule #21),
// read side uses the matching XOR on ds_read_b128.
// ---------------------------------------------------------------------------

typedef __attribute__((ext_vector_type(8))) short bf16x8;
typedef __attribute__((ext_vector_type(4))) float f32x4;

static __device__ __forceinline__ ushort f2b(float f) {
  uint32_t u = __float_as_uint(f);
  uint32_t r = (u + 0x7fffu + ((u >> 16) & 1u)) >> 16;  // RNE
  return (ushort)r;
}
static __device__ __forceinline__ float b2f(ushort b) {
  return __uint_as_float(((uint32_t)b) << 16);
}

#define GLOAD_LDS16(gp, lp)                                        \
  __builtin_amdgcn_global_load_lds(                                \
      (const __attribute__((address_space(1))) void*)(gp),         \
      (__attribute__((address_space(3))) void*)(lp), 16, 0, 0)

// ---------------- CSR build ----------------
__global__ __launch_bounds__(256) void hist_k(const int* __restrict__ dst,
                                              int* __restrict__ counts, int E) {
  int e = blockIdx.x * 256 + threadIdx.x;
  if (e < E) atomicAdd(&counts[dst[e]], 1);
}

__global__ __launch_bounds__(1024) void scan_k(const int* __restrict__ counts,
                                               int* __restrict__ rowptr,
                                               int* __restrict__ cursor, int N) {
  __shared__ int sums[1024];
  const int t = threadIdx.x;
  const int per = (N + 1023) >> 10;
  const int i0 = t * per;
  const int i1 = min(i0 + per, N);
  int s = 0;
  for (int i = i0; i < i1; ++i) s += counts[i];
  sums[t] = s;
  __syncthreads();
  for (int off = 1; off < 1024; off <<= 1) {
    int v = (t >= off) ? sums[t - off] : 0;
    __syncthreads();
    sums[t] += v;
    __syncthreads();
  }
  int run = t ? sums[t - 1] : 0;
  for (int i = i0; i < i1; ++i) {
    rowptr[i] = run;
    cursor[i] = run;
    run += counts[i];
  }
  if (t == 1023) rowptr[N] = sums[1023];
}

__global__ __launch_bounds__(256) void scatter_k(const int* __restrict__ dst,
                                                 int* __restrict__ cursor,
                                                 int* __restrict__ csr, int E) {
  int e = blockIdx.x * 256 + threadIdx.x;
  if (e < E) {
    int p = atomicAdd(&cursor[dst[e]], 1);
    csr[p] = e;
  }
}

__global__ __launch_bounds__(256) void master_k(const int* __restrict__ batch,
                                                int* __restrict__ master, int N) {
  int i = blockIdx.x * 256 + threadIdx.x;
  if (i < N) {
    int b = batch[i];
    if (i == N - 1 || batch[i + 1] != b) master[b] = i;
  }
}

// ---------------- conversions ----------------
__global__ __launch_bounds__(256) void cvt_k(const float* __restrict__ in,
                                             ushort* __restrict__ out, int n4) {
  int i = blockIdx.x * 256 + threadIdx.x;
  if (i < n4) {
    float4 v = ((const float4*)in)[i];
    ushort4 o;
    o.x = f2b(v.x); o.y = f2b(v.y); o.z = f2b(v.z); o.w = f2b(v.w);
    ((ushort4*)out)[i] = o;
  }
}

// out[(row_off+n)*K + k] = bf16(W[k*N + n])   (transpose+convert; tiny)
__global__ __launch_bounds__(256) void wt_k(const float* __restrict__ W,
                                            ushort* __restrict__ out,
                                            int K, int N, int row_off) {
  int i = blockIdx.x * 256 + threadIdx.x;
  if (i < N * K) {
    int n = i / K, k = i - n * K;
    out[(size_t)(row_off + n) * K + k] = f2b(W[(size_t)k * N + n]);
  }
}

// ---------------- bf16 MFMA GEMM ----------------
// C[M,N] = A[M,K] @ Bt[N,K]^T. 128x128 tile, BK=64, 4 waves (2x2), 64x64/wave.
// global_load_lds staging: LDS dest is linear (base+lane*16); the XOR swizzle
// (kslot ^= row&7) is applied to the per-lane GLOBAL source k-slot, and the
// same XOR on the ds_read side. N must be a multiple of 128, K of 64.
__global__ __launch_bounds__(256) void gemm_bf16(const ushort* __restrict__ A,
                                                 const ushort* __restrict__ Bt,
                                                 ushort* __restrict__ C,
                                                 int M, int N, int K) {
  __shared__ ushort As[128 * 64];
  __shared__ ushort Bs[128 * 64];
  const int tid = threadIdx.x;
  const int lane = tid & 63;
  const int wave = tid >> 6;
  const int bm = blockIdx.x * 128;
  const int bn = blockIdx.y * 128;
  const int wm = (wave >> 1) * 64;
  const int wn = (wave & 1) * 64;
  const int l15 = lane & 15;
  const int t_hi = lane >> 4;

  f32x4 acc[4][4] = {};

  // staging geometry: flat slot j in [0,1024); each slot is 16B (8 ushort).
  // slot j holds LDS row (j>>3), k-slot (j&7); content fetched from global
  // k-slot (j&7)^(row&7)  -> swizzled-in-source, linear-in-dest.
  const int wb64 = tid & ~63;  // wave-uniform flat base (issue i adds i*256)
  int jrow[4], jks[4];
#pragma unroll
  for (int i = 0; i < 4; ++i) {
    const int j = i * 256 + wb64 + lane;
    jrow[i] = j >> 3;
    jks[i] = (j & 7) ^ (jrow[i] & 7);
  }

  for (int k0 = 0; k0 < K; k0 += 64) {
#pragma unroll
    for (int i = 0; i < 4; ++i) {
      const int ar = min(bm + jrow[i], M - 1);  // clamp tail rows
      GLOAD_LDS16(A + (size_t)ar * K + k0 + jks[i] * 8,
                  As + (size_t)(i * 256 + wb64) * 8);
    }
#pragma unroll
    for (int i = 0; i < 4; ++i) {
      GLOAD_LDS16(Bt + (size_t)(bn + jrow[i]) * K + k0 + jks[i] * 8,
                  Bs + (size_t)(i * 256 + wb64) * 8);
    }
    __syncthreads();  // vmcnt(0) drain + barrier: tiles visible to all waves
#pragma unroll
    for (int ks = 0; ks < 2; ++ks) {
      bf16x8 af[4], bfr[4];
#pragma unroll
      for (int f = 0; f < 4; ++f) {
        const int q = (ks * 4 + t_hi) ^ (lane & 7);
        af[f]  = *(const bf16x8*)&As[(wm + f * 16 + l15) * 64 + q * 8];
        bfr[f] = *(const bf16x8*)&Bs[(wn + f * 16 + l15) * 64 + q * 8];
      }
#pragma unroll
      for (int fm = 0; fm < 4; ++fm)
#pragma unroll
        for (int fn = 0; fn < 4; ++fn)
          acc[fm][fn] = __builtin_amdgcn_mfma_f32_16x16x32_bf16(
              af[fm], bfr[fn], acc[fm][fn], 0, 0, 0);
    }
    __syncthreads();  // all waves done reading before next stage overwrites
  }
#pragma unroll
  for (int fm = 0; fm < 4; ++fm) {
    const int r0 = bm + wm + fm * 16 + t_hi * 4;
#pragma unroll
    for (int j = 0; j < 4; ++j) {
      const int gr = r0 + j;
      if (gr < M) {
#pragma unroll
        for (int fn = 0; fn < 4; ++fn) {
          const int gc = bn + wn + fn * 16 + l15;
          C[(size_t)gr * N + gc] = f2b(acc[fm][fn][j]);
        }
      }
    }
  }
}

// ---------------- edge logits (elementwise) ----------------
// one wave per edge: q = lrelu(eproj[e] + xl[src] + xr[dst]); logit[h]=sum q*att
__global__ __launch_bounds__(256) void logits_k(
    const ushort* __restrict__ xlr, const ushort* __restrict__ eproj,
    const float* __restrict__ att, const int* __restrict__ src,
    const int* __restrict__ dst, float* __restrict__ logits,
    int e0, int e1) {
  const int lane = threadIdx.x & 63;
  const int gw = (int)((blockIdx.x * blockDim.x + threadIdx.x) >> 6);
  const int nw = (int)((gridDim.x * blockDim.x) >> 6);
  const float a0 = att[4 * lane + 0], a1 = att[4 * lane + 1];
  const float a2 = att[4 * lane + 2], a3 = att[4 * lane + 3];
  for (int e = e0 + gw; e < e1; e += nw) {
    const int s = src[e], d = dst[e];
    ushort4 ue = *(const ushort4*)(eproj + (((size_t)(e - e0)) << 8) + lane * 4);
    ushort4 us = *(const ushort4*)(xlr + (((size_t)s) << 9) + lane * 4);
    ushort4 ud = *(const ushort4*)(xlr + (((size_t)d) << 9) + 256 + lane * 4);
    float q0 = b2f(ue.x) + b2f(us.x) + b2f(ud.x);
    float q1 = b2f(ue.y) + b2f(us.y) + b2f(ud.y);
    float q2 = b2f(ue.z) + b2f(us.z) + b2f(ud.z);
    float q3 = b2f(ue.w) + b2f(us.w) + b2f(ud.w);
    q0 = q0 > 0.f ? q0 : 0.2f * q0;
    q1 = q1 > 0.f ? q1 : 0.2f * q1;
    q2 = q2 > 0.f ? q2 : 0.2f * q2;
    q3 = q3 > 0.f ? q3 : 0.2f * q3;
    float p = q0 * a0 + q1 * a1 + q2 * a2 + q3 * a3;
    p += __shfl_xor(p, 1);
    p += __shfl_xor(p, 2);
    p += __shfl_xor(p, 4);
    p += __shfl_xor(p, 8);
    p += __shfl_xor(p, 16);
    if ((lane & 31) == 0) logits[2 * (size_t)e + (lane >> 5)] = p;
  }
}

// ---------------- per-node segment softmax + aggregation ----------------
__global__ __launch_bounds__(256) void aggregate_k(
    const ushort* __restrict__ xlr, const float* __restrict__ logits,
    const int* __restrict__ rowptr, const int* __restrict__ csr,
    const int* __restrict__ src, const float* __restrict__ bias,
    ushort* __restrict__ hb, float* __restrict__ hf, int N, int relu) {
  const int n = blockIdx.x * 4 + (threadIdx.x >> 6);
  if (n >= N) return;
  const int lane = threadIdx.x & 63;
  const int beg = rowptr[n], end = rowptr[n + 1];
  float m0 = -1e30f, m1 = -1e30f;
  for (int i = beg; i < end; ++i) {
    const int e = csr[i];
    m0 = fmaxf(m0, logits[2 * (size_t)e]);
    m1 = fmaxf(m1, logits[2 * (size_t)e + 1]);
  }
  float s0 = 0.f, s1 = 0.f, a00 = 0.f, a01 = 0.f, a10 = 0.f, a11 = 0.f;
  for (int i = beg; i < end; ++i) {
    const int e = csr[i];
    const float w0 = __expf(logits[2 * (size_t)e] - m0);
    const float w1 = __expf(logits[2 * (size_t)e + 1] - m1);
    s0 += w0; s1 += w1;
    const ushort* xs = xlr + (((size_t)src[e]) << 9);
    a00 += w0 * b2f(xs[lane]);
    a01 += w0 * b2f(xs[64 + lane]);
    a10 += w1 * b2f(xs[128 + lane]);
    a11 += w1 * b2f(xs[192 + lane]);
  }
  const float i0 = 1.f / (s0 + 1e-16f), i1 = 1.f / (s1 + 1e-16f);
  float o0 = 0.5f * (a00 * i0 + a10 * i1) + bias[lane];
  float o1 = 0.5f * (a01 * i0 + a11 * i1) + bias[64 + lane];
  if (relu) { o0 = fmaxf(o0, 0.f); o1 = fmaxf(o1, 0.f); }
  hb[(size_t)n * 128 + lane] = f2b(o0);
  hb[(size_t)n * 128 + 64 + lane] = f2b(o1);
  if (hf) {
    hf[(size_t)n * 128 + lane] = o0;
    hf[(size_t)n * 128 + 64 + lane] = o1;
  }
}

__global__ __launch_bounds__(128) void gather_k(const float* __restrict__ h,
                                                const int* __restrict__ master,
                                                float* __restrict__ out) {
  out[(size_t)blockIdx.x * 128 + threadIdx.x] =
      h[(size_t)master[blockIdx.x] * 128 + threadIdx.x];
}

// ---------------------------------------------------------------------------
#define CHUNK_E 100352  // 784 * 128

extern "C" void kernel_launch(void* const* d_in, const int* in_sizes, int n_in,
                              void* d_out, int out_size, void* d_ws, size_t ws_size,
                              hipStream_t stream) {
  const float* x     = (const float*)d_in[0];
  const int*   ei    = (const int*)d_in[1];
  const float* eattr = (const float*)d_in[2];
  const int*   batch = (const int*)d_in[3];

  const int N  = in_sizes[3];
  const int E  = in_sizes[1] / 2;
  const int IN = in_sizes[0] / N;
  const int B  = out_size / 128;

  const int* src  = ei;
  const int* dstp = ei + E;

  char* p = (char*)d_ws;
  auto carve = [&](size_t bytes) {
    void* r = (void*)p;
    p += (bytes + 255) & ~(size_t)255;
    return r;
  };
  ushort* xb    = (ushort*)carve((size_t)N * 512 * 2);   // bf16(x); dead after L1 GEMM
  ushort* eb    = (ushort*)carve((size_t)E * 64 * 2);    // bf16(edge_attr)
  ushort* xlr   = (ushort*)carve((size_t)N * 512 * 2);   // [xl | xr] bf16
  ushort* eproj = (ushort*)carve((size_t)CHUNK_E * 256 * 2);
  ushort* h1b   = (ushort*)carve((size_t)N * 128 * 2);
  ushort* h2b   = (ushort*)carve((size_t)N * 128 * 2);
  ushort* wt    = (ushort*)carve((size_t)512 * 512 * 2); // [wl|wr]^T bf16
  ushort* wet   = (ushort*)carve((size_t)256 * 64 * 2);  // we^T bf16
  float* logits = (float*)carve((size_t)E * 2 * 4);
  int* counts   = (int*)carve(((size_t)N + B) * 4);
  int* master   = counts + N;
  int* rowptr   = (int*)carve(((size_t)N + 1) * 4);
  int* cursor   = (int*)carve((size_t)N * 4);
  int* csr      = (int*)carve((size_t)E * 4);
  float* hf     = (float*)xb;  // f32 h3 aliases dead xb
  (void)ws_size; (void)n_in;

  // CSR + masters (reused by all 3 layers)
  hipMemsetAsync(counts, 0, ((size_t)N + B) * 4, stream);
  hist_k<<<(E + 255) / 256, 256, 0, stream>>>(dstp, counts, E);
  scan_k<<<1, 1024, 0, stream>>>(counts, rowptr, cursor, N);
  scatter_k<<<(E + 255) / 256, 256, 0, stream>>>(dstp, cursor, csr, E);
  master_k<<<(N + 255) / 256, 256, 0, stream>>>(batch, master, N);

  // bf16 conversions of the big inputs
  {
    int n4 = N * IN / 4;
    cvt_k<<<(n4 + 255) / 256, 256, 0, stream>>>(x, xb, n4);
    int e4 = E * 64 / 4;
    cvt_k<<<(e4 + 255) / 256, 256, 0, stream>>>(eattr, eb, e4);
  }

  const int agg_grid = (N + 3) / 4;
  for (int l = 0; l < 3; ++l) {
    const float* wl  = (const float*)d_in[4 + 5 * l + 0];
    const float* wr  = (const float*)d_in[4 + 5 * l + 1];
    const float* we  = (const float*)d_in[4 + 5 * l + 2];
    const float* att = (const float*)d_in[4 + 5 * l + 3];
    const float* bv  = (const float*)d_in[4 + 5 * l + 4];
    const int K = (l == 0) ? IN : 128;

    // weights -> bf16 transposed [n][k]
    wt_k<<<(256 * K + 255) / 256, 256, 0, stream>>>(wl, wt, K, 256, 0);
    wt_k<<<(256 * K + 255) / 256, 256, 0, stream>>>(wr, wt, K, 256, 256);
    wt_k<<<(256 * 64 + 255) / 256, 256, 0, stream>>>(we, wet, 64, 256, 0);

    const ushort* Ab = (l == 0) ? xb : ((l == 1) ? h1b : h2b);
    gemm_bf16<<<dim3((N + 127) / 128, 4), 256, 0, stream>>>(Ab, wt, xlr, N, 512, K);

    // edge projection + logits, chunked
    for (int c0 = 0; c0 < E; c0 += CHUNK_E) {
      const int Mc = min(CHUNK_E, E - c0);
      gemm_bf16<<<dim3((Mc + 127) / 128, 2), 256, 0, stream>>>(
          eb + (size_t)c0 * 64, wet, eproj, Mc, 256, 64);
      logits_k<<<1024, 256, 0, stream>>>(xlr, eproj, att, src, dstp, logits,
                                         c0, c0 + Mc);
    }

    ushort* hb = (l == 0) ? h1b : ((l == 1) ? h2b : h1b);
    aggregate_k<<<agg_grid, 256, 0, stream>>>(xlr, logits, rowptr, csr, src, bv,
                                              hb, (l == 2) ? hf : nullptr, N,
                                              l < 2 ? 1 : 0);
  }

  gather_k<<<B, 128, 0, stream>>>(hf, master, (float*)d_out);
}

// Round 4
// 857.405 us; speedup vs baseline: 2.9024x; 1.3666x over previous
//
#include <hip/hip_runtime.h>
#include <cstdint>
#include <cstddef>

// ---------------------------------------------------------------------------
// GATv2 x3 + master pooling, bf16-MFMA, fused edge pipeline.
// Per layer:
//   xlr = bf16(A) @ bf16([wl|wr])   (MFMA GEMM, N=512)
//   edge_fused_k: MFMA(wet, eb) -> eproj in regs -> +xl[s]+xr[d], lrelu,
//                 dot att, reduce -> logit scattered to CSR slot (payload)
//   aggregate_k: payload-ordered segment softmax + weighted gather (2 nodes/wave)
// CSR (+srcs, pos) built once per call, reused by all 3 layers.
// ---------------------------------------------------------------------------

typedef __attribute__((ext_vector_type(8))) short bf16x8;
typedef __attribute__((ext_vector_type(4))) float f32x4;
typedef __attribute__((ext_vector_type(8))) unsigned short u16x8;

static __device__ __forceinline__ ushort f2b(float f) {
  uint32_t u = __float_as_uint(f);
  uint32_t r = (u + 0x7fffu + ((u >> 16) & 1u)) >> 16;  // RNE
  return (ushort)r;
}
static __device__ __forceinline__ float b2f(ushort b) {
  return __uint_as_float(((uint32_t)b) << 16);
}

#define GLOAD_LDS16(gp, lp)                                        \
  __builtin_amdgcn_global_load_lds(                                \
      (const __attribute__((address_space(1))) void*)(gp),         \
      (__attribute__((address_space(3))) void*)(lp), 16, 0, 0)

// ---------------- CSR build ----------------
__global__ __launch_bounds__(256) void hist_k(const int* __restrict__ dst,
                                              int* __restrict__ counts, int E) {
  int e = blockIdx.x * 256 + threadIdx.x;
  if (e < E) atomicAdd(&counts[dst[e]], 1);
}

__global__ __launch_bounds__(1024) void scan_k(const int* __restrict__ counts,
                                               int* __restrict__ rowptr,
                                               int* __restrict__ cursor, int N) {
  __shared__ int sums[1024];
  const int t = threadIdx.x;
  const int per = (N + 1023) >> 10;
  const int i0 = t * per;
  const int i1 = min(i0 + per, N);
  int s = 0;
  for (int i = i0; i < i1; ++i) s += counts[i];
  sums[t] = s;
  __syncthreads();
  for (int off = 1; off < 1024; off <<= 1) {
    int v = (t >= off) ? sums[t - off] : 0;
    __syncthreads();
    sums[t] += v;
    __syncthreads();
  }
  int run = t ? sums[t - 1] : 0;
  for (int i = i0; i < i1; ++i) {
    rowptr[i] = run;
    cursor[i] = run;
    run += counts[i];
  }
  if (t == 1023) rowptr[N] = sums[1023];
}

// csr[p]=e and srcs[p]=src[e] (payload companions, layer-invariant)
__global__ __launch_bounds__(256) void scatter_k(const int* __restrict__ dst,
                                                 const int* __restrict__ src,
                                                 int* __restrict__ cursor,
                                                 int* __restrict__ csr,
                                                 int* __restrict__ srcs, int E) {
  int e = blockIdx.x * 256 + threadIdx.x;
  if (e < E) {
    int p = atomicAdd(&cursor[dst[e]], 1);
    csr[p] = e;
    srcs[p] = src[e];
  }
}

// pos[e] = CSR slot of edge e (so producers can scatter straight into payload)
__global__ __launch_bounds__(256) void pos_k(const int* __restrict__ csr,
                                             int* __restrict__ pos, int E) {
  int i = blockIdx.x * 256 + threadIdx.x;
  if (i < E) pos[csr[i]] = i;
}

__global__ __launch_bounds__(256) void master_k(const int* __restrict__ batch,
                                                int* __restrict__ master, int N) {
  int i = blockIdx.x * 256 + threadIdx.x;
  if (i < N) {
    int b = batch[i];
    if (i == N - 1 || batch[i + 1] != b) master[b] = i;
  }
}

// ---------------- conversions ----------------
__global__ __launch_bounds__(256) void cvt_k(const float* __restrict__ in,
                                             ushort* __restrict__ out, int n4) {
  int i = blockIdx.x * 256 + threadIdx.x;
  if (i < n4) {
    float4 v = ((const float4*)in)[i];
    ushort4 o;
    o.x = f2b(v.x); o.y = f2b(v.y); o.z = f2b(v.z); o.w = f2b(v.w);
    ((ushort4*)out)[i] = o;
  }
}

// out[(row_off+n)*K + k] = bf16(W[k*N + n])   (transpose+convert; tiny)
__global__ __launch_bounds__(256) void wt_k(const float* __restrict__ W,
                                            ushort* __restrict__ out,
                                            int K, int N, int row_off) {
  int i = blockIdx.x * 256 + threadIdx.x;
  if (i < N * K) {
    int n = i / K, k = i - n * K;
    out[(size_t)(row_off + n) * K + k] = f2b(W[(size_t)k * N + n]);
  }
}

// ---------------- bf16 MFMA GEMM (node features) ----------------
// C[M,N] = A[M,K] @ Bt[N,K]^T. 128x128 tile, BK=64, 4 waves (2x2), 64x64/wave.
// global_load_lds staging; swizzle-on-source (rule #21), XOR on ds_read side.
__global__ __launch_bounds__(256) void gemm_bf16(const ushort* __restrict__ A,
                                                 const ushort* __restrict__ Bt,
                                                 ushort* __restrict__ C,
                                                 int M, int N, int K) {
  __shared__ ushort As[128 * 64];
  __shared__ ushort Bs[128 * 64];
  const int tid = threadIdx.x;
  const int lane = tid & 63;
  const int wave = tid >> 6;
  const int bm = blockIdx.x * 128;
  const int bn = blockIdx.y * 128;
  const int wm = (wave >> 1) * 64;
  const int wn = (wave & 1) * 64;
  const int l15 = lane & 15;
  const int t_hi = lane >> 4;

  f32x4 acc[4][4] = {};

  const int wb64 = tid & ~63;
  int jrow[4], jks[4];
#pragma unroll
  for (int i = 0; i < 4; ++i) {
    const int j = i * 256 + wb64 + lane;
    jrow[i] = j >> 3;
    jks[i] = (j & 7) ^ (jrow[i] & 7);
  }

  for (int k0 = 0; k0 < K; k0 += 64) {
#pragma unroll
    for (int i = 0; i < 4; ++i) {
      const int ar = min(bm + jrow[i], M - 1);
      GLOAD_LDS16(A + (size_t)ar * K + k0 + jks[i] * 8,
                  As + (size_t)(i * 256 + wb64) * 8);
    }
#pragma unroll
    for (int i = 0; i < 4; ++i) {
      GLOAD_LDS16(Bt + (size_t)(bn + jrow[i]) * K + k0 + jks[i] * 8,
                  Bs + (size_t)(i * 256 + wb64) * 8);
    }
    __syncthreads();
#pragma unroll
    for (int ks = 0; ks < 2; ++ks) {
      bf16x8 af[4], bfr[4];
#pragma unroll
      for (int f = 0; f < 4; ++f) {
        const int q = (ks * 4 + t_hi) ^ (lane & 7);
        af[f]  = *(const bf16x8*)&As[(wm + f * 16 + l15) * 64 + q * 8];
        bfr[f] = *(const bf16x8*)&Bs[(wn + f * 16 + l15) * 64 + q * 8];
      }
#pragma unroll
      for (int fm = 0; fm < 4; ++fm)
#pragma unroll
        for (int fn = 0; fn < 4; ++fn)
          acc[fm][fn] = __builtin_amdgcn_mfma_f32_16x16x32_bf16(
              af[fm], bfr[fn], acc[fm][fn], 0, 0, 0);
    }
    __syncthreads();
  }
#pragma unroll
  for (int fm = 0; fm < 4; ++fm) {
    const int r0 = bm + wm + fm * 16 + t_hi * 4;
#pragma unroll
    for (int j = 0; j < 4; ++j) {
      const int gr = r0 + j;
      if (gr < M) {
#pragma unroll
        for (int fn = 0; fn < 4; ++fn) {
          const int gc = bn + wn + fn * 16 + l15;
          C[(size_t)gr * N + gc] = f2b(acc[fm][fn][j]);
        }
      }
    }
  }
}

// ---------------- fused edge projection + logits ----------------
// grid (ceil(E/128), 2 heads). Swapped MFMA: A = wet rows (this head's 128 c's),
// B = eb rows (128 edges). acc row = c, col = edge. Epilogue adds gathered
// xl[src]/xr[dst], lrelu, dot att, reduces over c, scatters logit into
// payload[pos[e]] (CSR order) for the aggregation pass.
__global__ __launch_bounds__(256) void edge_fused_k(
    const ushort* __restrict__ eb,   // [E][64]
    const ushort* __restrict__ wet,  // [256][64]
    const ushort* __restrict__ xlr,  // [N][512]
    const float* __restrict__ att,   // [256]
    const int* __restrict__ src, const int* __restrict__ dst,
    const int* __restrict__ pos, float* __restrict__ payload_f, int E) {
  __shared__ ushort As[128 * 64];
  __shared__ ushort Bs[128 * 64];
  __shared__ int sSrc[128], sDst[128];
  __shared__ float red[256];

  const int tid = threadIdx.x;
  const int lane = tid & 63;
  const int wave = tid >> 6;
  const int bm = blockIdx.x * 128;     // edge base
  const int h = blockIdx.y;            // head
  const int wm = (wave >> 1) * 64;     // c-dim offset within head
  const int wn = (wave & 1) * 64;      // edge offset within tile
  const int l15 = lane & 15;
  const int t_hi = lane >> 4;

  if (tid < 128) {
    const int e = min(bm + tid, E - 1);
    sSrc[tid] = src[e];
    sDst[tid] = dst[e];
  }

  f32x4 acc[4][4] = {};

  const int wb64 = tid & ~63;
  int jrow[4], jks[4];
#pragma unroll
  for (int i = 0; i < 4; ++i) {
    const int j = i * 256 + wb64 + lane;
    jrow[i] = j >> 3;
    jks[i] = (j & 7) ^ (jrow[i] & 7);
  }

  // single K-step (K = 64)
#pragma unroll
  for (int i = 0; i < 4; ++i) {
    GLOAD_LDS16(wet + (size_t)((h << 7) + jrow[i]) * 64 + jks[i] * 8,
                As + (size_t)(i * 256 + wb64) * 8);
  }
#pragma unroll
  for (int i = 0; i < 4; ++i) {
    const int er = min(bm + jrow[i], E - 1);
    GLOAD_LDS16(eb + (size_t)er * 64 + jks[i] * 8,
                Bs + (size_t)(i * 256 + wb64) * 8);
  }
  __syncthreads();
#pragma unroll
  for (int ks = 0; ks < 2; ++ks) {
    bf16x8 af[4], bfr[4];
#pragma unroll
    for (int f = 0; f < 4; ++f) {
      const int q = (ks * 4 + t_hi) ^ (lane & 7);
      af[f]  = *(const bf16x8*)&As[(wm + f * 16 + l15) * 64 + q * 8];
      bfr[f] = *(const bf16x8*)&Bs[(wn + f * 16 + l15) * 64 + q * 8];
    }
#pragma unroll
    for (int fm = 0; fm < 4; ++fm)
#pragma unroll
      for (int fn = 0; fn < 4; ++fn)
        acc[fm][fn] = __builtin_amdgcn_mfma_f32_16x16x32_bf16(
            af[fm], bfr[fn], acc[fm][fn], 0, 0, 0);
  }

  // epilogue: per lane, 4 edges (fn), 16 c-values each (fm x j)
  float p[4];
#pragma unroll
  for (int fn = 0; fn < 4; ++fn) {
    const int el = wn + fn * 16 + l15;
    const int s = sSrc[el];
    const int d = sDst[el];
    const ushort* xlp = xlr + (((size_t)s) << 9) + (h << 7) + wm + t_hi * 4;
    const ushort* xrp = xlr + (((size_t)d) << 9) + 256 + (h << 7) + wm + t_hi * 4;
    float ap = 0.f;
#pragma unroll
    for (int fm = 0; fm < 4; ++fm) {
      const ushort4 xa = *(const ushort4*)(xlp + fm * 16);
      const ushort4 xc = *(const ushort4*)(xrp + fm * 16);
      const float4 at4 = *(const float4*)(att + (h << 7) + wm + fm * 16 + t_hi * 4);
      float q0 = acc[fm][fn][0] + b2f(xa.x) + b2f(xc.x);
      float q1 = acc[fm][fn][1] + b2f(xa.y) + b2f(xc.y);
      float q2 = acc[fm][fn][2] + b2f(xa.z) + b2f(xc.z);
      float q3 = acc[fm][fn][3] + b2f(xa.w) + b2f(xc.w);
      q0 = q0 > 0.f ? q0 : 0.2f * q0;
      q1 = q1 > 0.f ? q1 : 0.2f * q1;
      q2 = q2 > 0.f ? q2 : 0.2f * q2;
      q3 = q3 > 0.f ? q3 : 0.2f * q3;
      ap += q0 * at4.x + q1 * at4.y + q2 * at4.z + q3 * at4.w;
    }
    p[fn] = ap;
  }
#pragma unroll
  for (int fn = 0; fn < 4; ++fn) {
    p[fn] += __shfl_xor(p[fn], 16);
    p[fn] += __shfl_xor(p[fn], 32);
  }
  if (lane < 16) {
#pragma unroll
    for (int fn = 0; fn < 4; ++fn)
      red[(wave >> 1) * 128 + wn + fn * 16 + lane] = p[fn];
  }
  __syncthreads();
  if (tid < 128) {
    const int e = bm + tid;
    if (e < E) {
      const float v = red[tid] + red[128 + tid];
      payload_f[2 * (size_t)pos[e] + h] = v;
    }
  }
}

// ---------------- per-node segment softmax + aggregation ----------------
// 2 nodes per wave (32 lanes each); lane covers 8 cols via one 16B gather.
__global__ __launch_bounds__(256) void aggregate_k(
    const ushort* __restrict__ xlr, const float2* __restrict__ payload,
    const int* __restrict__ rowptr, const int* __restrict__ srcs,
    const float* __restrict__ bias, ushort* __restrict__ hb,
    float* __restrict__ hf, int N, int relu) {
  const int n = blockIdx.x * 8 + (threadIdx.x >> 5);
  if (n >= N) return;
  const int sl = threadIdx.x & 31;
  const int hsel = sl >> 4;  // 0: head0 cols (0..127), 1: head1 (128..255)
  const int beg = rowptr[n], end = rowptr[n + 1];

  float m0 = -1e30f, m1 = -1e30f;
  for (int i = beg; i < end; ++i) {
    const float2 lg = payload[i];
    m0 = fmaxf(m0, lg.x);
    m1 = fmaxf(m1, lg.y);
  }
  float s0 = 0.f, s1 = 0.f;
  float acc[8] = {};
  for (int i = beg; i < end; ++i) {
    const float2 lg = payload[i];
    const float w0 = __expf(lg.x - m0);
    const float w1 = __expf(lg.y - m1);
    s0 += w0; s1 += w1;
    const float w = hsel ? w1 : w0;
    const u16x8 v = *(const u16x8*)(xlr + (((size_t)srcs[i]) << 9) + sl * 8);
#pragma unroll
    for (int t = 0; t < 8; ++t) acc[t] += w * b2f((ushort)v[t]);
  }
  const float i0 = 1.f / (s0 + 1e-16f);
  const float i1 = 1.f / (s1 + 1e-16f);
  const float myinv = hsel ? i1 : i0;
  const int c0 = (sl & 15) * 8;
  float o[8];
#pragma unroll
  for (int t = 0; t < 8; ++t) {
    const float mine = acc[t] * myinv;
    const float other = __shfl_xor(mine, 16);
    float v = 0.5f * (mine + other) + bias[c0 + t];
    if (relu) v = fmaxf(v, 0.f);
    o[t] = v;
  }
  if (sl < 16) {
    u16x8 ob;
#pragma unroll
    for (int t = 0; t < 8; ++t) ob[t] = f2b(o[t]);
    *(u16x8*)(hb + (size_t)n * 128 + c0) = ob;
    if (hf) {
      *(float4*)(hf + (size_t)n * 128 + c0) = make_float4(o[0], o[1], o[2], o[3]);
      *(float4*)(hf + (size_t)n * 128 + c0 + 4) = make_float4(o[4], o[5], o[6], o[7]);
    }
  }
}

__global__ __launch_bounds__(128) void gather_k(const float* __restrict__ h,
                                                const int* __restrict__ master,
                                                float* __restrict__ out) {
  out[(size_t)blockIdx.x * 128 + threadIdx.x] =
      h[(size_t)master[blockIdx.x] * 128 + threadIdx.x];
}

// ---------------------------------------------------------------------------
extern "C" void kernel_launch(void* const* d_in, const int* in_sizes, int n_in,
                              void* d_out, int out_size, void* d_ws, size_t ws_size,
                              hipStream_t stream) {
  const float* x     = (const float*)d_in[0];
  const int*   ei    = (const int*)d_in[1];
  const float* eattr = (const float*)d_in[2];
  const int*   batch = (const int*)d_in[3];

  const int N  = in_sizes[3];
  const int E  = in_sizes[1] / 2;
  const int IN = in_sizes[0] / N;
  const int B  = out_size / 128;

  const int* src  = ei;
  const int* dstp = ei + E;

  char* p = (char*)d_ws;
  auto carve = [&](size_t bytes) {
    void* r = (void*)p;
    p += (bytes + 255) & ~(size_t)255;
    return r;
  };
  ushort* xb     = (ushort*)carve((size_t)N * 512 * 2);  // bf16(x); dead after L1 GEMM
  ushort* eb     = (ushort*)carve((size_t)E * 64 * 2);   // bf16(edge_attr)
  ushort* xlr    = (ushort*)carve((size_t)N * 512 * 2);  // [xl | xr] bf16
  ushort* h1b    = (ushort*)carve((size_t)N * 128 * 2);
  ushort* h2b    = (ushort*)carve((size_t)N * 128 * 2);
  ushort* wt     = (ushort*)carve((size_t)512 * 512 * 2);
  ushort* wet    = (ushort*)carve((size_t)256 * 64 * 2);
  float2* payload= (float2*)carve((size_t)E * 8);        // CSR-ordered logits
  int* counts    = (int*)carve(((size_t)N + B) * 4);
  int* master    = counts + N;
  int* rowptr    = (int*)carve(((size_t)N + 1) * 4);
  int* cursor    = (int*)carve((size_t)N * 4);
  int* csr       = (int*)carve((size_t)E * 4);
  int* srcs      = (int*)carve((size_t)E * 4);           // src in CSR order
  int* pos       = (int*)carve((size_t)E * 4);           // edge -> CSR slot
  float* hf      = (float*)xb;                            // f32 h3 aliases dead xb
  (void)ws_size; (void)n_in;

  // CSR + companions + masters (once; reused by all 3 layers)
  hipMemsetAsync(counts, 0, ((size_t)N + B) * 4, stream);
  hist_k<<<(E + 255) / 256, 256, 0, stream>>>(dstp, counts, E);
  scan_k<<<1, 1024, 0, stream>>>(counts, rowptr, cursor, N);
  scatter_k<<<(E + 255) / 256, 256, 0, stream>>>(dstp, src, cursor, csr, srcs, E);
  pos_k<<<(E + 255) / 256, 256, 0, stream>>>(csr, pos, E);
  master_k<<<(N + 255) / 256, 256, 0, stream>>>(batch, master, N);

  // bf16 conversions of the big inputs
  {
    int n4 = N * IN / 4;
    cvt_k<<<(n4 + 255) / 256, 256, 0, stream>>>(x, xb, n4);
    int e4 = E * 64 / 4;
    cvt_k<<<(e4 + 255) / 256, 256, 0, stream>>>(eattr, eb, e4);
  }

  const dim3 edge_grid((E + 127) / 128, 2);
  const int agg_grid = (N + 7) / 8;
  for (int l = 0; l < 3; ++l) {
    const float* wl  = (const float*)d_in[4 + 5 * l + 0];
    const float* wr  = (const float*)d_in[4 + 5 * l + 1];
    const float* we  = (const float*)d_in[4 + 5 * l + 2];
    const float* att = (const float*)d_in[4 + 5 * l + 3];
    const float* bv  = (const float*)d_in[4 + 5 * l + 4];
    const int K = (l == 0) ? IN : 128;

    wt_k<<<(256 * K + 255) / 256, 256, 0, stream>>>(wl, wt, K, 256, 0);
    wt_k<<<(256 * K + 255) / 256, 256, 0, stream>>>(wr, wt, K, 256, 256);
    wt_k<<<(256 * 64 + 255) / 256, 256, 0, stream>>>(we, wet, 64, 256, 0);

    const ushort* Ab = (l == 0) ? xb : ((l == 1) ? h1b : h2b);
    gemm_bf16<<<dim3((N + 127) / 128, 4), 256, 0, stream>>>(Ab, wt, xlr, N, 512, K);

    edge_fused_k<<<edge_grid, 256, 0, stream>>>(eb, wet, xlr, att, src, dstp,
                                                pos, (float*)payload, E);

    ushort* hb = (l == 0) ? h1b : ((l == 1) ? h2b : h1b);
    aggregate_k<<<agg_grid, 256, 0, stream>>>(xlr, payload, rowptr, srcs, bv,
                                              hb, (l == 2) ? hf : nullptr, N,
                                              l < 2 ? 1 : 0);
  }

  gather_k<<<B, 128, 0, stream>>>(hf, master, (float*)d_out);
}

// Round 5
// 761.181 us; speedup vs baseline: 3.2693x; 1.1264x over previous
//
#include <hip/hip_runtime.h>
#include <cstdint>
#include <cstddef>

// ---------------------------------------------------------------------------
// GATv2 x3 + master pooling, bf16-MFMA, CSR-ordered fused edge pipeline.
// Setup (once): CSR over dst (csr, srcs, dsts, rowptr), edge_attr permuted
//   into CSR order + bf16 (ebc), masters.
// Per layer:
//   xlr = bf16(A) @ bf16([wl|wr])   (MFMA GEMM, N=512)
//   edge_fused_k (CSR order): MFMA(wet, ebc-tile) + gathered xl[s]/xr[d],
//     lrelu, dot att, reduce -> payload[i] sequential write
//   aggregate_k: segment softmax + weighted gather, even/odd wave-half split
// ---------------------------------------------------------------------------

typedef __attribute__((ext_vector_type(8))) short bf16x8;
typedef __attribute__((ext_vector_type(4))) float f32x4;
typedef __attribute__((ext_vector_type(8))) unsigned short u16x8;

static __device__ __forceinline__ ushort f2b(float f) {
  uint32_t u = __float_as_uint(f);
  uint32_t r = (u + 0x7fffu + ((u >> 16) & 1u)) >> 16;  // RNE
  return (ushort)r;
}
static __device__ __forceinline__ float b2f(ushort b) {
  return __uint_as_float(((uint32_t)b) << 16);
}

#define GLOAD_LDS16(gp, lp)                                        \
  __builtin_amdgcn_global_load_lds(                                \
      (const __attribute__((address_space(1))) void*)(gp),         \
      (__attribute__((address_space(3))) void*)(lp), 16, 0, 0)

// ---------------- CSR build ----------------
__global__ __launch_bounds__(256) void hist_k(const int* __restrict__ dst,
                                              int* __restrict__ counts, int E) {
  int e = blockIdx.x * 256 + threadIdx.x;
  if (e < E) atomicAdd(&counts[dst[e]], 1);
}

__global__ __launch_bounds__(1024) void scan_k(const int* __restrict__ counts,
                                               int* __restrict__ rowptr,
                                               int* __restrict__ cursor, int N) {
  __shared__ int sums[1024];
  const int t = threadIdx.x;
  const int per = (N + 1023) >> 10;
  const int i0 = t * per;
  const int i1 = min(i0 + per, N);
  int s = 0;
  for (int i = i0; i < i1; ++i) s += counts[i];
  sums[t] = s;
  __syncthreads();
  for (int off = 1; off < 1024; off <<= 1) {
    int v = (t >= off) ? sums[t - off] : 0;
    __syncthreads();
    sums[t] += v;
    __syncthreads();
  }
  int run = t ? sums[t - 1] : 0;
  for (int i = i0; i < i1; ++i) {
    rowptr[i] = run;
    cursor[i] = run;
    run += counts[i];
  }
  if (t == 1023) rowptr[N] = sums[1023];
}

// csr[p]=e, srcs[p]=src[e], dsts[p]=dst[e]  (slot companions, layer-invariant)
__global__ __launch_bounds__(256) void scatter_k(const int* __restrict__ dst,
                                                 const int* __restrict__ src,
                                                 int* __restrict__ cursor,
                                                 int* __restrict__ csr,
                                                 int* __restrict__ srcs,
                                                 int* __restrict__ dsts, int E) {
  int e = blockIdx.x * 256 + threadIdx.x;
  if (e < E) {
    int p = atomicAdd(&cursor[dst[e]], 1);
    csr[p] = e;
    srcs[p] = src[e];
    dsts[p] = dst[e];
  }
}

__global__ __launch_bounds__(256) void master_k(const int* __restrict__ batch,
                                                int* __restrict__ master, int N) {
  int i = blockIdx.x * 256 + threadIdx.x;
  if (i < N) {
    int b = batch[i];
    if (i == N - 1 || batch[i + 1] != b) master[b] = i;
  }
}

// ---------------- conversions ----------------
__global__ __launch_bounds__(256) void cvt_k(const float* __restrict__ in,
                                             ushort* __restrict__ out, int n4) {
  int i = blockIdx.x * 256 + threadIdx.x;
  if (i < n4) {
    float4 v = ((const float4*)in)[i];
    ushort4 o;
    o.x = f2b(v.x); o.y = f2b(v.y); o.z = f2b(v.z); o.w = f2b(v.w);
    ((ushort4*)out)[i] = o;
  }
}

// ebc[i][:] = bf16(edge_attr[csr[i]][:])  (gather rows into CSR order, once)
__global__ __launch_bounds__(256) void ebp_cvt_k(const float* __restrict__ ea,
                                                 const int* __restrict__ csr,
                                                 ushort* __restrict__ ebc, int E) {
  const int idx = blockIdx.x * 256 + threadIdx.x;
  const int i = idx >> 4, t = idx & 15;
  if (i < E) {
    float4 v = *(const float4*)(ea + (size_t)csr[i] * 64 + t * 4);
    ushort4 o;
    o.x = f2b(v.x); o.y = f2b(v.y); o.z = f2b(v.z); o.w = f2b(v.w);
    *(ushort4*)(ebc + (size_t)i * 64 + t * 4) = o;
  }
}

// out[(row_off+n)*K + k] = bf16(W[k*N + n])   (transpose+convert; tiny)
__global__ __launch_bounds__(256) void wt_k(const float* __restrict__ W,
                                            ushort* __restrict__ out,
                                            int K, int N, int row_off) {
  int i = blockIdx.x * 256 + threadIdx.x;
  if (i < N * K) {
    int n = i / K, k = i - n * K;
    out[(size_t)(row_off + n) * K + k] = f2b(W[(size_t)k * N + n]);
  }
}

// ---------------- bf16 MFMA GEMM (node features) ----------------
// C[M,N] = A[M,K] @ Bt[N,K]^T. 128x128 tile, BK=64, 4 waves (2x2), 64x64/wave.
// global_load_lds staging; swizzle-on-source (rule #21), XOR on ds_read side.
__global__ __launch_bounds__(256) void gemm_bf16(const ushort* __restrict__ A,
                                                 const ushort* __restrict__ Bt,
                                                 ushort* __restrict__ C,
                                                 int M, int N, int K) {
  __shared__ ushort As[128 * 64];
  __shared__ ushort Bs[128 * 64];
  const int tid = threadIdx.x;
  const int lane = tid & 63;
  const int wave = tid >> 6;
  const int bm = blockIdx.x * 128;
  const int bn = blockIdx.y * 128;
  const int wm = (wave >> 1) * 64;
  const int wn = (wave & 1) * 64;
  const int l15 = lane & 15;
  const int t_hi = lane >> 4;

  f32x4 acc[4][4] = {};

  const int wb64 = tid & ~63;
  int jrow[4], jks[4];
#pragma unroll
  for (int i = 0; i < 4; ++i) {
    const int j = i * 256 + wb64 + lane;
    jrow[i] = j >> 3;
    jks[i] = (j & 7) ^ (jrow[i] & 7);
  }

  for (int k0 = 0; k0 < K; k0 += 64) {
#pragma unroll
    for (int i = 0; i < 4; ++i) {
      const int ar = min(bm + jrow[i], M - 1);
      GLOAD_LDS16(A + (size_t)ar * K + k0 + jks[i] * 8,
                  As + (size_t)(i * 256 + wb64) * 8);
    }
#pragma unroll
    for (int i = 0; i < 4; ++i) {
      GLOAD_LDS16(Bt + (size_t)(bn + jrow[i]) * K + k0 + jks[i] * 8,
                  Bs + (size_t)(i * 256 + wb64) * 8);
    }
    __syncthreads();
#pragma unroll
    for (int ks = 0; ks < 2; ++ks) {
      bf16x8 af[4], bfr[4];
#pragma unroll
      for (int f = 0; f < 4; ++f) {
        const int q = (ks * 4 + t_hi) ^ (lane & 7);
        af[f]  = *(const bf16x8*)&As[(wm + f * 16 + l15) * 64 + q * 8];
        bfr[f] = *(const bf16x8*)&Bs[(wn + f * 16 + l15) * 64 + q * 8];
      }
#pragma unroll
      for (int fm = 0; fm < 4; ++fm)
#pragma unroll
        for (int fn = 0; fn < 4; ++fn)
          acc[fm][fn] = __builtin_amdgcn_mfma_f32_16x16x32_bf16(
              af[fm], bfr[fn], acc[fm][fn], 0, 0, 0);
    }
    __syncthreads();
  }
#pragma unroll
  for (int fm = 0; fm < 4; ++fm) {
    const int r0 = bm + wm + fm * 16 + t_hi * 4;
#pragma unroll
    for (int j = 0; j < 4; ++j) {
      const int gr = r0 + j;
      if (gr < M) {
#pragma unroll
        for (int fn = 0; fn < 4; ++fn) {
          const int gc = bn + wn + fn * 16 + l15;
          C[(size_t)gr * N + gc] = f2b(acc[fm][fn][j]);
        }
      }
    }
  }
}

// ---------------- fused edge projection + logits (CSR order) ----------------
// grid (ceil(E/128), 2 heads). Swapped MFMA: A = wet rows (head's 128 c's,
// read DIRECT from global - L1-resident), B = ebc rows (128 CSR slots, LDS).
// acc row = c, col = slot. Epilogue adds gathered xl[srcs]/xr[dsts] (dsts
// sorted -> cache-friendly), lrelu, dot att, reduce over c, sequential
// payload[i] write.
__global__ __launch_bounds__(256) void edge_fused_k(
    const ushort* __restrict__ ebc,  // [E][64] CSR-ordered
    const ushort* __restrict__ wet,  // [256][64]
    const ushort* __restrict__ xlr,  // [N][512]
    const float* __restrict__ att,   // [256]
    const int* __restrict__ srcs, const int* __restrict__ dsts,
    float* __restrict__ payload_f, int E) {
  __shared__ ushort Bs[128 * 64];
  __shared__ int sSrc[128], sDst[128];
  __shared__ float red[256];

  const int tid = threadIdx.x;
  const int lane = tid & 63;
  const int wave = tid >> 6;
  const int bm = blockIdx.x * 128;     // CSR slot base
  const int h = blockIdx.y;            // head
  const int wm = (wave >> 1) * 64;     // c-dim offset within head
  const int wn = (wave & 1) * 64;      // slot offset within tile
  const int l15 = lane & 15;
  const int t_hi = lane >> 4;

  if (tid < 128) {
    const int i = min(bm + tid, E - 1);
    sSrc[tid] = srcs[i];
    sDst[tid] = dsts[i];
  }

  f32x4 acc[4][4] = {};

  // stage ebc tile (single K-step, K=64); swizzle-on-source
  const int wb64 = tid & ~63;
#pragma unroll
  for (int i = 0; i < 4; ++i) {
    const int j = i * 256 + wb64 + lane;
    const int jrow = j >> 3;
    const int jks = (j & 7) ^ (jrow & 7);
    const int er = min(bm + jrow, E - 1);
    GLOAD_LDS16(ebc + (size_t)er * 64 + jks * 8,
                Bs + (size_t)(i * 256 + wb64) * 8);
  }
  __syncthreads();
#pragma unroll
  for (int ks = 0; ks < 2; ++ks) {
    bf16x8 af[4], bfr[4];
#pragma unroll
    for (int f = 0; f < 4; ++f) {
      const int q = (ks * 4 + t_hi) ^ (lane & 7);
      bfr[f] = *(const bf16x8*)&Bs[(wn + f * 16 + l15) * 64 + q * 8];
      af[f] = *(const bf16x8*)&wet[(size_t)((h << 7) + wm + f * 16 + l15) * 64 +
                                   (ks * 4 + t_hi) * 8];
    }
#pragma unroll
    for (int fm = 0; fm < 4; ++fm)
#pragma unroll
      for (int fn = 0; fn < 4; ++fn)
        acc[fm][fn] = __builtin_amdgcn_mfma_f32_16x16x32_bf16(
            af[fm], bfr[fn], acc[fm][fn], 0, 0, 0);
  }

  // epilogue: per lane, 4 slots (fn), 16 c-values each (fm x j)
  float p[4];
#pragma unroll
  for (int fn = 0; fn < 4; ++fn) {
    const int el = wn + fn * 16 + l15;
    const int s = sSrc[el];
    const int d = sDst[el];
    const ushort* xlp = xlr + (((size_t)s) << 9) + (h << 7) + wm + t_hi * 4;
    const ushort* xrp = xlr + (((size_t)d) << 9) + 256 + (h << 7) + wm + t_hi * 4;
    float ap = 0.f;
#pragma unroll
    for (int fm = 0; fm < 4; ++fm) {
      const ushort4 xa = *(const ushort4*)(xlp + fm * 16);
      const ushort4 xc = *(const ushort4*)(xrp + fm * 16);
      const float4 at4 = *(const float4*)(att + (h << 7) + wm + fm * 16 + t_hi * 4);
      float q0 = acc[fm][fn][0] + b2f(xa.x) + b2f(xc.x);
      float q1 = acc[fm][fn][1] + b2f(xa.y) + b2f(xc.y);
      float q2 = acc[fm][fn][2] + b2f(xa.z) + b2f(xc.z);
      float q3 = acc[fm][fn][3] + b2f(xa.w) + b2f(xc.w);
      q0 = q0 > 0.f ? q0 : 0.2f * q0;
      q1 = q1 > 0.f ? q1 : 0.2f * q1;
      q2 = q2 > 0.f ? q2 : 0.2f * q2;
      q3 = q3 > 0.f ? q3 : 0.2f * q3;
      ap += q0 * at4.x + q1 * at4.y + q2 * at4.z + q3 * at4.w;
    }
    p[fn] = ap;
  }
#pragma unroll
  for (int fn = 0; fn < 4; ++fn) {
    p[fn] += __shfl_xor(p[fn], 16);
    p[fn] += __shfl_xor(p[fn], 32);
  }
  if (lane < 16) {
#pragma unroll
    for (int fn = 0; fn < 4; ++fn)
      red[(wave >> 1) * 128 + wn + fn * 16 + lane] = p[fn];
  }
  __syncthreads();
  if (tid < 128) {
    const int i = bm + tid;
    if (i < E) payload_f[2 * (size_t)i + h] = red[tid] + red[128 + tid];
  }
}

// ---------------- per-node segment softmax + aggregation ----------------
// one wave per node; lanes 0-31 take even CSR slots, 32-63 odd (2x MLP);
// within a 32-group, lanes 0-15 = head0 weights, 16-31 = head1.
__global__ __launch_bounds__(256) void aggregate_k(
    const ushort* __restrict__ xlr, const float2* __restrict__ payload,
    const int* __restrict__ rowptr, const int* __restrict__ srcs,
    const float* __restrict__ bias, ushort* __restrict__ hb,
    float* __restrict__ hf, int N, int relu) {
  const int n = blockIdx.x * 4 + (threadIdx.x >> 6);
  if (n >= N) return;
  const int lane = threadIdx.x & 63;
  const int half = lane >> 5;
  const int sl = lane & 31;
  const int hsel = sl >> 4;
  const int beg = rowptr[n], end = rowptr[n + 1];

  float m0 = -1e30f, m1 = -1e30f;
  for (int i = beg + half; i < end; i += 2) {
    const float2 lg = payload[i];
    m0 = fmaxf(m0, lg.x);
    m1 = fmaxf(m1, lg.y);
  }
  m0 = fmaxf(m0, __shfl_xor(m0, 32));
  m1 = fmaxf(m1, __shfl_xor(m1, 32));

  float s0 = 0.f, s1 = 0.f;
  float acc[8] = {};
  for (int i = beg + half; i < end; i += 2) {
    const float2 lg = payload[i];
    const float w0 = __expf(lg.x - m0);
    const float w1 = __expf(lg.y - m1);
    s0 += w0; s1 += w1;
    const float w = hsel ? w1 : w0;
    const u16x8 v = *(const u16x8*)(xlr + (((size_t)srcs[i]) << 9) + sl * 8);
#pragma unroll
    for (int t = 0; t < 8; ++t) acc[t] += w * b2f((ushort)v[t]);
  }
  s0 += __shfl_xor(s0, 32);
  s1 += __shfl_xor(s1, 32);
#pragma unroll
  for (int t = 0; t < 8; ++t) acc[t] += __shfl_xor(acc[t], 32);

  const float i0 = 1.f / (s0 + 1e-16f);
  const float i1 = 1.f / (s1 + 1e-16f);
  const float myinv = hsel ? i1 : i0;
  const int c0 = (sl & 15) * 8;
  float o[8];
#pragma unroll
  for (int t = 0; t < 8; ++t) {
    const float mine = acc[t] * myinv;
    const float other = __shfl_xor(mine, 16);
    float v = 0.5f * (mine + other) + bias[c0 + t];
    if (relu) v = fmaxf(v, 0.f);
    o[t] = v;
  }
  if (lane < 16) {
    u16x8 ob;
#pragma unroll
    for (int t = 0; t < 8; ++t) ob[t] = f2b(o[t]);
    *(u16x8*)(hb + (size_t)n * 128 + c0) = ob;
    if (hf) {
      *(float4*)(hf + (size_t)n * 128 + c0) = make_float4(o[0], o[1], o[2], o[3]);
      *(float4*)(hf + (size_t)n * 128 + c0 + 4) = make_float4(o[4], o[5], o[6], o[7]);
    }
  }
}

__global__ __launch_bounds__(128) void gather_k(const float* __restrict__ h,
                                                const int* __restrict__ master,
                                                float* __restrict__ out) {
  out[(size_t)blockIdx.x * 128 + threadIdx.x] =
      h[(size_t)master[blockIdx.x] * 128 + threadIdx.x];
}

// ---------------------------------------------------------------------------
extern "C" void kernel_launch(void* const* d_in, const int* in_sizes, int n_in,
                              void* d_out, int out_size, void* d_ws, size_t ws_size,
                              hipStream_t stream) {
  const float* x     = (const float*)d_in[0];
  const int*   ei    = (const int*)d_in[1];
  const float* eattr = (const float*)d_in[2];
  const int*   batch = (const int*)d_in[3];

  const int N  = in_sizes[3];
  const int E  = in_sizes[1] / 2;
  const int IN = in_sizes[0] / N;
  const int B  = out_size / 128;

  const int* src  = ei;
  const int* dstp = ei + E;

  char* p = (char*)d_ws;
  auto carve = [&](size_t bytes) {
    void* r = (void*)p;
    p += (bytes + 255) & ~(size_t)255;
    return r;
  };
  ushort* xb     = (ushort*)carve((size_t)N * 512 * 2);  // bf16(x); dead after L1 GEMM
  ushort* ebc    = (ushort*)carve((size_t)E * 64 * 2);   // bf16 edge_attr, CSR order
  ushort* xlr    = (ushort*)carve((size_t)N * 512 * 2);  // [xl | xr] bf16
  ushort* h1b    = (ushort*)carve((size_t)N * 128 * 2);
  ushort* h2b    = (ushort*)carve((size_t)N * 128 * 2);
  ushort* wt     = (ushort*)carve((size_t)512 * 512 * 2);
  ushort* wet    = (ushort*)carve((size_t)256 * 64 * 2);
  float2* payload= (float2*)carve((size_t)E * 8);        // CSR-ordered logits
  int* counts    = (int*)carve(((size_t)N + B) * 4);
  int* master    = counts + N;
  int* rowptr    = (int*)carve(((size_t)N + 1) * 4);
  int* cursor    = (int*)carve((size_t)N * 4);
  int* csr       = (int*)carve((size_t)E * 4);
  int* srcs      = (int*)carve((size_t)E * 4);           // src in CSR order
  int* dsts      = (int*)carve((size_t)E * 4);           // dst in CSR order
  float* hf      = (float*)xb;                            // f32 h3 aliases dead xb
  (void)ws_size; (void)n_in;

  // CSR + companions + masters + permuted edge_attr (once; reused 3 layers)
  hipMemsetAsync(counts, 0, ((size_t)N + B) * 4, stream);
  hist_k<<<(E + 255) / 256, 256, 0, stream>>>(dstp, counts, E);
  scan_k<<<1, 1024, 0, stream>>>(counts, rowptr, cursor, N);
  scatter_k<<<(E + 255) / 256, 256, 0, stream>>>(dstp, src, cursor, csr, srcs,
                                                 dsts, E);
  master_k<<<(N + 255) / 256, 256, 0, stream>>>(batch, master, N);
  ebp_cvt_k<<<(E * 16 + 255) / 256, 256, 0, stream>>>(eattr, csr, ebc, E);

  {
    int n4 = N * IN / 4;
    cvt_k<<<(n4 + 255) / 256, 256, 0, stream>>>(x, xb, n4);
  }

  const dim3 edge_grid((E + 127) / 128, 2);
  const int agg_grid = (N + 3) / 4;
  for (int l = 0; l < 3; ++l) {
    const float* wl  = (const float*)d_in[4 + 5 * l + 0];
    const float* wr  = (const float*)d_in[4 + 5 * l + 1];
    const float* we  = (const float*)d_in[4 + 5 * l + 2];
    const float* att = (const float*)d_in[4 + 5 * l + 3];
    const float* bv  = (const float*)d_in[4 + 5 * l + 4];
    const int K = (l == 0) ? IN : 128;

    wt_k<<<(256 * K + 255) / 256, 256, 0, stream>>>(wl, wt, K, 256, 0);
    wt_k<<<(256 * K + 255) / 256, 256, 0, stream>>>(wr, wt, K, 256, 256);
    wt_k<<<(256 * 64 + 255) / 256, 256, 0, stream>>>(we, wet, 64, 256, 0);

    const ushort* Ab = (l == 0) ? xb : ((l == 1) ? h1b : h2b);
    gemm_bf16<<<dim3((N + 127) / 128, 4), 256, 0, stream>>>(Ab, wt, xlr, N, 512, K);

    edge_fused_k<<<edge_grid, 256, 0, stream>>>(ebc, wet, xlr, att, srcs, dsts,
                                                (float*)payload, E);

    ushort* hb = (l == 0) ? h1b : ((l == 1) ? h2b : h1b);
    aggregate_k<<<agg_grid, 256, 0, stream>>>(xlr, payload, rowptr, srcs, bv,
                                              hb, (l == 2) ? hf : nullptr, N,
                                              l < 2 ? 1 : 0);
  }

  gather_k<<<B, 128, 0, stream>>>(hf, master, (float*)d_out);
}

// Round 6
// 645.492 us; speedup vs baseline: 3.8553x; 1.1792x over previous
//
#include <hip/hip_runtime.h>
#include <cstdint>
#include <cstddef>

// ---------------------------------------------------------------------------
// GATv2 x3 + master pooling, bf16-MFMA, CSR-ordered fused edge pipeline.
// Setup (once): CSR over dst (srcs, dsts, rowptr via parallel scan),
//   edge_attr permuted into CSR order + bf16 (ebc), masters, all weight
//   transposes fused into one kernel.
// Per layer:
//   xlr = bf16(A) @ bf16([wl|wr])   (MFMA GEMM, N=512)
//   edge_fused_k (CSR order, both heads): MFMA(wet, ebc-tile) + gathered
//     xl[s]/xr[d], lrelu, dot att, reduce -> payload[i] sequential write
//   aggregate_k: segment softmax + weighted gather, even/odd wave-half split
// ---------------------------------------------------------------------------

typedef __attribute__((ext_vector_type(8))) short bf16x8;
typedef __attribute__((ext_vector_type(4))) float f32x4;
typedef __attribute__((ext_vector_type(8))) unsigned short u16x8;

static __device__ __forceinline__ ushort f2b(float f) {
  uint32_t u = __float_as_uint(f);
  uint32_t r = (u + 0x7fffu + ((u >> 16) & 1u)) >> 16;  // RNE
  return (ushort)r;
}
static __device__ __forceinline__ float b2f(ushort b) {
  return __uint_as_float(((uint32_t)b) << 16);
}

#define GLOAD_LDS16(gp, lp)                                        \
  __builtin_amdgcn_global_load_lds(                                \
      (const __attribute__((address_space(1))) void*)(gp),         \
      (__attribute__((address_space(3))) void*)(lp), 16, 0, 0)

// ---------------- CSR build ----------------
__global__ __launch_bounds__(256) void hist_k(const int* __restrict__ dst,
                                              int* __restrict__ counts, int E) {
  int e = blockIdx.x * 256 + threadIdx.x;
  if (e < E) atomicAdd(&counts[dst[e]], 1);
}

// parallel exclusive scan over counts[N]: 1024-elem chunks per block
#define SCAN_CHUNK 1024
__global__ __launch_bounds__(256) void scan_sum_k(const int* __restrict__ counts,
                                                  int* __restrict__ bsum, int N) {
  __shared__ int ws[4];
  const int t = threadIdx.x;
  const int i0 = blockIdx.x * SCAN_CHUNK + t * 4;
  int s = 0;
  if (i0 + 3 < N) {
    int4 v = *(const int4*)(counts + i0);
    s = v.x + v.y + v.z + v.w;
  } else {
    for (int k = 0; k < 4; ++k)
      if (i0 + k < N) s += counts[i0 + k];
  }
  for (int off = 1; off < 64; off <<= 1) s += __shfl_xor(s, off);
  if ((t & 63) == 0) ws[t >> 6] = s;
  __syncthreads();
  if (t == 0) bsum[blockIdx.x] = ws[0] + ws[1] + ws[2] + ws[3];
}

__global__ __launch_bounds__(256) void scan_bsum_k(int* __restrict__ bsum, int G) {
  __shared__ int tmp[256];
  const int t = threadIdx.x;
  const int v = (t < G) ? bsum[t] : 0;
  tmp[t] = v;
  __syncthreads();
  for (int off = 1; off < 256; off <<= 1) {
    int u = (t >= off) ? tmp[t - off] : 0;
    __syncthreads();
    tmp[t] += u;
    __syncthreads();
  }
  if (t < G) bsum[t] = tmp[t] - v;  // exclusive
}

__global__ __launch_bounds__(256) void scan_out_k(const int* __restrict__ counts,
                                                  const int* __restrict__ bsum,
                                                  int* __restrict__ rowptr,
                                                  int* __restrict__ cursor,
                                                  int N, int E) {
  __shared__ int wsum[4];
  const int t = threadIdx.x;
  const int lane = t & 63, w = t >> 6;
  const int i0 = blockIdx.x * SCAN_CHUNK + t * 4;
  int v[4] = {0, 0, 0, 0};
  if (i0 + 3 < N) {
    int4 q = *(const int4*)(counts + i0);
    v[0] = q.x; v[1] = q.y; v[2] = q.z; v[3] = q.w;
  } else {
    for (int k = 0; k < 4; ++k)
      if (i0 + k < N) v[k] = counts[i0 + k];
  }
  const int s = v[0] + v[1] + v[2] + v[3];
  int inc = s;
  for (int off = 1; off < 64; off <<= 1) {
    int u = __shfl_up(inc, off);
    if (lane >= off) inc += u;
  }
  if (lane == 63) wsum[w] = inc;
  __syncthreads();
  int wpre = 0;
  for (int k = 0; k < w; ++k) wpre += wsum[k];
  int run = bsum[blockIdx.x] + wpre + inc - s;  // exclusive prefix
  for (int k = 0; k < 4; ++k) {
    const int i = i0 + k;
    if (i < N) {
      rowptr[i] = run;
      cursor[i] = run;
      run += v[k];
    }
  }
  if (blockIdx.x == 0 && t == 0) rowptr[N] = E;
}

// csr[p]=e, srcs[p]=src[e], dsts[p]=dst[e]  (slot companions, layer-invariant)
__global__ __launch_bounds__(256) void scatter_k(const int* __restrict__ dst,
                                                 const int* __restrict__ src,
                                                 int* __restrict__ cursor,
                                                 int* __restrict__ csr,
                                                 int* __restrict__ srcs,
                                                 int* __restrict__ dsts, int E) {
  int e = blockIdx.x * 256 + threadIdx.x;
  if (e < E) {
    int p = atomicAdd(&cursor[dst[e]], 1);
    csr[p] = e;
    srcs[p] = src[e];
    dsts[p] = dst[e];
  }
}

__global__ __launch_bounds__(256) void master_k(const int* __restrict__ batch,
                                                int* __restrict__ master, int N) {
  int i = blockIdx.x * 256 + threadIdx.x;
  if (i < N) {
    int b = batch[i];
    if (i == N - 1 || batch[i + 1] != b) master[b] = i;
  }
}

// ---------------- conversions ----------------
__global__ __launch_bounds__(256) void cvt_k(const float* __restrict__ in,
                                             ushort* __restrict__ out, int n4) {
  int i = blockIdx.x * 256 + threadIdx.x;
  if (i < n4) {
    float4 v = ((const float4*)in)[i];
    ushort4 o;
    o.x = f2b(v.x); o.y = f2b(v.y); o.z = f2b(v.z); o.w = f2b(v.w);
    ((ushort4*)out)[i] = o;
  }
}

// ebc[i][:] = bf16(edge_attr[csr[i]][:])  (gather rows into CSR order, once)
__global__ __launch_bounds__(256) void ebp_cvt_k(const float* __restrict__ ea,
                                                 const int* __restrict__ csr,
                                                 ushort* __restrict__ ebc, int E) {
  const int idx = blockIdx.x * 256 + threadIdx.x;
  const int i = idx >> 4, t = idx & 15;
  if (i < E) {
    float4 v = *(const float4*)(ea + (size_t)csr[i] * 64 + t * 4);
    ushort4 o;
    o.x = f2b(v.x); o.y = f2b(v.y); o.z = f2b(v.z); o.w = f2b(v.w);
    *(ushort4*)(ebc + (size_t)i * 64 + t * 4) = o;
  }
}

// all weight transposes (3 layers: [wl|wr]^T per layer + we^T x3), one launch
__global__ __launch_bounds__(256) void wtall_k(
    const float* __restrict__ w1l, const float* __restrict__ w1r,
    const float* __restrict__ w1e, const float* __restrict__ w2l,
    const float* __restrict__ w2r, const float* __restrict__ w2e,
    const float* __restrict__ w3l, const float* __restrict__ w3r,
    const float* __restrict__ w3e, ushort* __restrict__ wt0,
    ushort* __restrict__ wt1, ushort* __restrict__ wt2,
    ushort* __restrict__ wet, int IN) {
  const int y = blockIdx.y;
  const int i = blockIdx.x * 256 + threadIdx.x;
  if (y < 3) {
    const int K = (y == 0) ? IN : 128;
    ushort* out = (y == 0) ? wt0 : ((y == 1) ? wt1 : wt2);
    const float* Wl = (y == 0) ? w1l : ((y == 1) ? w2l : w3l);
    const float* Wr = (y == 0) ? w1r : ((y == 1) ? w2r : w3r);
    if (i < 512 * K) {
      const int n = i / K, k = i - n * K;
      const float* W = (n < 256) ? Wl : Wr;
      out[(size_t)n * K + k] = f2b(W[(size_t)k * 256 + (n & 255)]);
    }
  } else {
    if (i < 3 * 256 * 64) {
      const int l = i / (256 * 64);
      const int r = i - l * 256 * 64;
      const int n = r / 64, k = r - n * 64;
      const float* W = (l == 0) ? w1e : ((l == 1) ? w2e : w3e);
      wet[(size_t)l * 16384 + (size_t)n * 64 + k] = f2b(W[(size_t)k * 256 + n]);
    }
  }
}

// ---------------- bf16 MFMA GEMM (node features) ----------------
// C[M,N] = A[M,K] @ Bt[N,K]^T. 128x128 tile, BK=64, 4 waves (2x2), 64x64/wave.
// global_load_lds staging; swizzle-on-source (rule #21), XOR on ds_read side.
__global__ __launch_bounds__(256) void gemm_bf16(const ushort* __restrict__ A,
                                                 const ushort* __restrict__ Bt,
                                                 ushort* __restrict__ C,
                                                 int M, int N, int K) {
  __shared__ ushort As[128 * 64];
  __shared__ ushort Bs[128 * 64];
  const int tid = threadIdx.x;
  const int lane = tid & 63;
  const int wave = tid >> 6;
  const int bm = blockIdx.x * 128;
  const int bn = blockIdx.y * 128;
  const int wm = (wave >> 1) * 64;
  const int wn = (wave & 1) * 64;
  const int l15 = lane & 15;
  const int t_hi = lane >> 4;

  f32x4 acc[4][4] = {};

  const int wb64 = tid & ~63;
  int jrow[4], jks[4];
#pragma unroll
  for (int i = 0; i < 4; ++i) {
    const int j = i * 256 + wb64 + lane;
    jrow[i] = j >> 3;
    jks[i] = (j & 7) ^ (jrow[i] & 7);
  }

  for (int k0 = 0; k0 < K; k0 += 64) {
#pragma unroll
    for (int i = 0; i < 4; ++i) {
      const int ar = min(bm + jrow[i], M - 1);
      GLOAD_LDS16(A + (size_t)ar * K + k0 + jks[i] * 8,
                  As + (size_t)(i * 256 + wb64) * 8);
    }
#pragma unroll
    for (int i = 0; i < 4; ++i) {
      GLOAD_LDS16(Bt + (size_t)(bn + jrow[i]) * K + k0 + jks[i] * 8,
                  Bs + (size_t)(i * 256 + wb64) * 8);
    }
    __syncthreads();
#pragma unroll
    for (int ks = 0; ks < 2; ++ks) {
      bf16x8 af[4], bfr[4];
#pragma unroll
      for (int f = 0; f < 4; ++f) {
        const int q = (ks * 4 + t_hi) ^ (lane & 7);
        af[f]  = *(const bf16x8*)&As[(wm + f * 16 + l15) * 64 + q * 8];
        bfr[f] = *(const bf16x8*)&Bs[(wn + f * 16 + l15) * 64 + q * 8];
      }
#pragma unroll
      for (int fm = 0; fm < 4; ++fm)
#pragma unroll
        for (int fn = 0; fn < 4; ++fn)
          acc[fm][fn] = __builtin_amdgcn_mfma_f32_16x16x32_bf16(
              af[fm], bfr[fn], acc[fm][fn], 0, 0, 0);
    }
    __syncthreads();
  }
#pragma unroll
  for (int fm = 0; fm < 4; ++fm) {
    const int r0 = bm + wm + fm * 16 + t_hi * 4;
#pragma unroll
    for (int j = 0; j < 4; ++j) {
      const int gr = r0 + j;
      if (gr < M) {
#pragma unroll
        for (int fn = 0; fn < 4; ++fn) {
          const int gc = bn + wn + fn * 16 + l15;
          C[(size_t)gr * N + gc] = f2b(acc[fm][fn][j]);
        }
      }
    }
  }
}

// ---------------- fused edge projection + logits (CSR order, both heads) ----
// grid ceil(E/128), 512 threads (8 waves). Swapped MFMA: A = wet (all 256
// c-rows, direct from global - L1-resident), B = ebc tile (128 CSR slots,
// LDS). Wave (wm,wn): wm=(wave>>1)*64 covers c 0..255 (head = wm>>7),
// wn=(wave&1)*64 covers slots. Epilogue adds gathered xl[srcs] (cols 0..255,
// 512B contiguous) / xr[dsts] (cols 256..511), lrelu, dot att, reduce,
// sequential payload write.
__global__ __launch_bounds__(512) void edge_fused_k(
    const ushort* __restrict__ ebc,  // [E][64] CSR-ordered
    const ushort* __restrict__ wet,  // [256][64] (this layer)
    const ushort* __restrict__ xlr,  // [N][512]
    const float* __restrict__ att,   // [256]
    const int* __restrict__ srcs, const int* __restrict__ dsts,
    float* __restrict__ payload_f, int E) {
  __shared__ ushort Bs[128 * 64];     // 16KB
  __shared__ int sSrc[128], sDst[128];
  __shared__ float red[2][2][128];    // [head][c-group][slot]

  const int tid = threadIdx.x;
  const int lane = tid & 63;
  const int wave = tid >> 6;           // 0..7
  const int bm = blockIdx.x * 128;     // CSR slot base
  const int wm = (wave >> 1) * 64;     // c offset 0..255
  const int wn = (wave & 1) * 64;      // slot offset
  const int l15 = lane & 15;
  const int t_hi = lane >> 4;

  if (tid < 128) {
    const int i = min(bm + tid, E - 1);
    sSrc[tid] = srcs[i];
    sDst[tid] = dsts[i];
  }

  // stage ebc tile (K=64): 1024 16B slots, 512 threads, 2 each;
  // swizzle-on-source, linear LDS dest
  const int wb = tid & ~63;
#pragma unroll
  for (int i = 0; i < 2; ++i) {
    const int j = i * 512 + wb + lane;
    const int jrow = j >> 3;
    const int jks = (j & 7) ^ (jrow & 7);
    const int er = min(bm + jrow, E - 1);
    GLOAD_LDS16(ebc + (size_t)er * 64 + jks * 8,
                Bs + (size_t)(i * 512 + wb) * 8);
  }
  __syncthreads();

  f32x4 acc[4][4] = {};
#pragma unroll
  for (int ks = 0; ks < 2; ++ks) {
    bf16x8 af[4], bfr[4];
#pragma unroll
    for (int f = 0; f < 4; ++f) {
      const int q = (ks * 4 + t_hi) ^ (lane & 7);
      bfr[f] = *(const bf16x8*)&Bs[(wn + f * 16 + l15) * 64 + q * 8];
      af[f] = *(const bf16x8*)&wet[(size_t)(wm + f * 16 + l15) * 64 +
                                   (ks * 4 + t_hi) * 8];
    }
#pragma unroll
    for (int fm = 0; fm < 4; ++fm)
#pragma unroll
      for (int fn = 0; fn < 4; ++fn)
        acc[fm][fn] = __builtin_amdgcn_mfma_f32_16x16x32_bf16(
            af[fm], bfr[fn], acc[fm][fn], 0, 0, 0);
  }

  // epilogue: per lane, 4 slots (fn), 16 c-values each (fm x j)
  float p[4];
#pragma unroll
  for (int fn = 0; fn < 4; ++fn) {
    const int el = wn + fn * 16 + l15;
    const int s = sSrc[el];
    const int d = sDst[el];
    const ushort* xlp = xlr + (((size_t)s) << 9) + wm + t_hi * 4;
    const ushort* xrp = xlr + (((size_t)d) << 9) + 256 + wm + t_hi * 4;
    float ap = 0.f;
#pragma unroll
    for (int fm = 0; fm < 4; ++fm) {
      const ushort4 xa = *(const ushort4*)(xlp + fm * 16);
      const ushort4 xc = *(const ushort4*)(xrp + fm * 16);
      const float4 at4 = *(const float4*)(att + wm + fm * 16 + t_hi * 4);
      float q0 = acc[fm][fn][0] + b2f(xa.x) + b2f(xc.x);
      float q1 = acc[fm][fn][1] + b2f(xa.y) + b2f(xc.y);
      float q2 = acc[fm][fn][2] + b2f(xa.z) + b2f(xc.z);
      float q3 = acc[fm][fn][3] + b2f(xa.w) + b2f(xc.w);
      q0 = q0 > 0.f ? q0 : 0.2f * q0;
      q1 = q1 > 0.f ? q1 : 0.2f * q1;
      q2 = q2 > 0.f ? q2 : 0.2f * q2;
      q3 = q3 > 0.f ? q3 : 0.2f * q3;
      ap += q0 * at4.x + q1 * at4.y + q2 * at4.z + q3 * at4.w;
    }
    p[fn] = ap;
  }
#pragma unroll
  for (int fn = 0; fn < 4; ++fn) {
    p[fn] += __shfl_xor(p[fn], 16);
    p[fn] += __shfl_xor(p[fn], 32);
  }
  if (lane < 16) {
    const int h = wave >> 2;
    const int g = (wave >> 1) & 1;
#pragma unroll
    for (int fn = 0; fn < 4; ++fn)
      red[h][g][wn + fn * 16 + lane] = p[fn];
  }
  __syncthreads();
  if (tid < 256) {
    const int slot = tid & 127, h = tid >> 7;
    const int i = bm + slot;
    if (i < E) payload_f[2 * (size_t)i + h] = red[h][0][slot] + red[h][1][slot];
  }
}

// ---------------- per-node segment softmax + aggregation ----------------
// one wave per node; lanes 0-31 take even CSR slots, 32-63 odd (2x MLP);
// within a 32-group, lanes 0-15 = head0 weights, 16-31 = head1.
__global__ __launch_bounds__(256) void aggregate_k(
    const ushort* __restrict__ xlr, const float2* __restrict__ payload,
    const int* __restrict__ rowptr, const int* __restrict__ srcs,
    const float* __restrict__ bias, ushort* __restrict__ hb,
    float* __restrict__ hf, int N, int relu) {
  const int n = blockIdx.x * 4 + (threadIdx.x >> 6);
  if (n >= N) return;
  const int lane = threadIdx.x & 63;
  const int half = lane >> 5;
  const int sl = lane & 31;
  const int hsel = sl >> 4;
  const int beg = rowptr[n], end = rowptr[n + 1];

  float m0 = -1e30f, m1 = -1e30f;
  for (int i = beg + half; i < end; i += 2) {
    const float2 lg = payload[i];
    m0 = fmaxf(m0, lg.x);
    m1 = fmaxf(m1, lg.y);
  }
  m0 = fmaxf(m0, __shfl_xor(m0, 32));
  m1 = fmaxf(m1, __shfl_xor(m1, 32));

  float s0 = 0.f, s1 = 0.f;
  float acc[8] = {};
  for (int i = beg + half; i < end; i += 2) {
    const float2 lg = payload[i];
    const float w0 = __expf(lg.x - m0);
    const float w1 = __expf(lg.y - m1);
    s0 += w0; s1 += w1;
    const float w = hsel ? w1 : w0;
    const u16x8 v = *(const u16x8*)(xlr + (((size_t)srcs[i]) << 9) + sl * 8);
#pragma unroll
    for (int t = 0; t < 8; ++t) acc[t] += w * b2f((ushort)v[t]);
  }
  s0 += __shfl_xor(s0, 32);
  s1 += __shfl_xor(s1, 32);
#pragma unroll
  for (int t = 0; t < 8; ++t) acc[t] += __shfl_xor(acc[t], 32);

  const float i0 = 1.f / (s0 + 1e-16f);
  const float i1 = 1.f / (s1 + 1e-16f);
  const float myinv = hsel ? i1 : i0;
  const int c0 = (sl & 15) * 8;
  float o[8];
#pragma unroll
  for (int t = 0; t < 8; ++t) {
    const float mine = acc[t] * myinv;
    const float other = __shfl_xor(mine, 16);
    float v = 0.5f * (mine + other) + bias[c0 + t];
    if (relu) v = fmaxf(v, 0.f);
    o[t] = v;
  }
  if (lane < 16) {
    u16x8 ob;
#pragma unroll
    for (int t = 0; t < 8; ++t) ob[t] = f2b(o[t]);
    *(u16x8*)(hb + (size_t)n * 128 + c0) = ob;
    if (hf) {
      *(float4*)(hf + (size_t)n * 128 + c0) = make_float4(o[0], o[1], o[2], o[3]);
      *(float4*)(hf + (size_t)n * 128 + c0 + 4) = make_float4(o[4], o[5], o[6], o[7]);
    }
  }
}

__global__ __launch_bounds__(128) void gather_k(const float* __restrict__ h,
                                                const int* __restrict__ master,
                                                float* __restrict__ out) {
  out[(size_t)blockIdx.x * 128 + threadIdx.x] =
      h[(size_t)master[blockIdx.x] * 128 + threadIdx.x];
}

// ---------------------------------------------------------------------------
extern "C" void kernel_launch(void* const* d_in, const int* in_sizes, int n_in,
                              void* d_out, int out_size, void* d_ws, size_t ws_size,
                              hipStream_t stream) {
  const float* x     = (const float*)d_in[0];
  const int*   ei    = (const int*)d_in[1];
  const float* eattr = (const float*)d_in[2];
  const int*   batch = (const int*)d_in[3];

  const int N  = in_sizes[3];
  const int E  = in_sizes[1] / 2;
  const int IN = in_sizes[0] / N;
  const int B  = out_size / 128;

  const int* src  = ei;
  const int* dstp = ei + E;

  char* p = (char*)d_ws;
  auto carve = [&](size_t bytes) {
    void* r = (void*)p;
    p += (bytes + 255) & ~(size_t)255;
    return r;
  };
  ushort* xb     = (ushort*)carve((size_t)N * 512 * 2);  // bf16(x); dead after L1 GEMM
  ushort* ebc    = (ushort*)carve((size_t)E * 64 * 2);   // bf16 edge_attr, CSR order
  ushort* xlr    = (ushort*)carve((size_t)N * 512 * 2);  // [xl | xr] bf16
  ushort* h1b    = (ushort*)carve((size_t)N * 128 * 2);
  ushort* h2b    = (ushort*)carve((size_t)N * 128 * 2);
  ushort* wt0    = (ushort*)carve((size_t)512 * 512 * 2);
  ushort* wt1    = (ushort*)carve((size_t)512 * 128 * 2);
  ushort* wt2    = (ushort*)carve((size_t)512 * 128 * 2);
  ushort* wet    = (ushort*)carve((size_t)3 * 256 * 64 * 2);
  float2* payload= (float2*)carve((size_t)E * 8);        // CSR-ordered logits
  int* counts    = (int*)carve(((size_t)N + B) * 4);
  int* master    = counts + N;
  int* rowptr    = (int*)carve(((size_t)N + 1) * 4);
  int* cursor    = (int*)carve((size_t)N * 4);
  int* csr       = (int*)carve((size_t)E * 4);
  int* srcs      = (int*)carve((size_t)E * 4);           // src in CSR order
  int* dsts      = (int*)carve((size_t)E * 4);           // dst in CSR order
  int* bsum      = (int*)carve(256 * 4);
  float* hf      = (float*)xb;                            // f32 h3 aliases dead xb
  (void)ws_size; (void)n_in;

  const int G = (N + SCAN_CHUNK - 1) / SCAN_CHUNK;

  // CSR + companions + masters + permuted edge_attr (once; reused 3 layers)
  hipMemsetAsync(counts, 0, ((size_t)N + B) * 4, stream);
  hist_k<<<(E + 255) / 256, 256, 0, stream>>>(dstp, counts, E);
  scan_sum_k<<<G, 256, 0, stream>>>(counts, bsum, N);
  scan_bsum_k<<<1, 256, 0, stream>>>(bsum, G);
  scan_out_k<<<G, 256, 0, stream>>>(counts, bsum, rowptr, cursor, N, E);
  scatter_k<<<(E + 255) / 256, 256, 0, stream>>>(dstp, src, cursor, csr, srcs,
                                                 dsts, E);
  master_k<<<(N + 255) / 256, 256, 0, stream>>>(batch, master, N);
  ebp_cvt_k<<<(E * 16 + 255) / 256, 256, 0, stream>>>(eattr, csr, ebc, E);

  {
    int n4 = N * IN / 4;
    cvt_k<<<(n4 + 255) / 256, 256, 0, stream>>>(x, xb, n4);
  }

  // all weight transposes, one launch
  wtall_k<<<dim3((512 * IN + 255) / 256, 4), 256, 0, stream>>>(
      (const float*)d_in[4], (const float*)d_in[5], (const float*)d_in[6],
      (const float*)d_in[9], (const float*)d_in[10], (const float*)d_in[11],
      (const float*)d_in[14], (const float*)d_in[15], (const float*)d_in[16],
      wt0, wt1, wt2, wet, IN);

  const int edge_grid = (E + 127) / 128;
  const int agg_grid = (N + 3) / 4;
  ushort* wts[3] = {wt0, wt1, wt2};
  for (int l = 0; l < 3; ++l) {
    const float* att = (const float*)d_in[4 + 5 * l + 3];
    const float* bv  = (const float*)d_in[4 + 5 * l + 4];
    const int K = (l == 0) ? IN : 128;

    const ushort* Ab = (l == 0) ? xb : ((l == 1) ? h1b : h2b);
    gemm_bf16<<<dim3((N + 127) / 128, 4), 256, 0, stream>>>(Ab, wts[l], xlr,
                                                            N, 512, K);

    edge_fused_k<<<edge_grid, 512, 0, stream>>>(ebc, wet + (size_t)l * 16384,
                                                xlr, att, srcs, dsts,
                                                (float*)payload, E);

    ushort* hb = (l == 0) ? h1b : ((l == 1) ? h2b : h1b);
    aggregate_k<<<agg_grid, 256, 0, stream>>>(xlr, payload, rowptr, srcs, bv,
                                              hb, (l == 2) ? hf : nullptr, N,
                                              l < 2 ? 1 : 0);
  }

  gather_k<<<B, 128, 0, stream>>>(hf, master, (float*)d_out);
}